// Round 1
// baseline (1636.915 us; speedup 1.0000x reference)
//
#include <hip/hip_runtime.h>
#include <hip/hip_bf16.h>
#include <math.h>

// Problem constants
#define LYR 2
#define DIM 128
#define NH 4
#define HD 32
#define BB 2
#define NN 4096
#define MROWS (BB * NN)          // 8192
#define SCALE 0.17677669529663687f   // 1/sqrt(32)
#define R2 0.0625f               // (WINDOW/2)^2
#define BN_EPS 1e-5f

// ---------------------------------------------------------------------------
// BatchNorm: partial sums (sum, sumsq) per feature via atomics
// grid 64 x 256. Each block covers 128 rows. Thread t always sees feature t%128.
__global__ __launch_bounds__(256) void bn_stats_k(const float* __restrict__ x,
                                                  float* __restrict__ sums) {
  __shared__ float ss[256], sq[256];
  const int t = threadIdx.x;
  const size_t base = (size_t)blockIdx.x * (128 * DIM);
  float s = 0.f, qq = 0.f;
  for (int idx = t; idx < 128 * DIM; idx += 256) {
    float vv = x[base + idx];
    s += vv; qq += vv * vv;
  }
  ss[t] = s; sq[t] = qq;
  __syncthreads();
  if (t < 128) {
    float s2 = ss[t] + ss[t + 128];
    float q2 = sq[t] + sq[t + 128];
    atomicAdd(&sums[t], s2);
    atomicAdd(&sums[128 + t], q2);
  }
}

// y = (x-mu)*rsqrt(var+eps)*g + b ; grid 4096 x 256 (exactly 1M elements)
__global__ __launch_bounds__(256) void bn_apply_k(const float* __restrict__ x,
                                                  const float* __restrict__ sums,
                                                  const float* __restrict__ g,
                                                  const float* __restrict__ bta,
                                                  float* __restrict__ y) {
  const int idx = blockIdx.x * 256 + threadIdx.x;
  const int dd = idx & (DIM - 1);
  const float inv = 1.0f / (float)MROWS;
  float mu = sums[dd] * inv;
  float var = sums[128 + dd] * inv - mu * mu;
  float rs = rsqrtf(var + BN_EPS);
  y[idx] = (x[idx] - mu) * rs * g[dd] + bta[dd];
}

// ---------------------------------------------------------------------------
// fp32 GEMM: C[M,Nn] = A[M,K] @ W[K,Nn] + bias (+res) (ReLU optional)
// BM=BN=64, BK=16, 256 threads, 4x4 per thread.
template <bool RELU, bool RES>
__global__ __launch_bounds__(256) void gemm_k(const float* __restrict__ A,
                                              const float* __restrict__ W,
                                              const float* __restrict__ bias,
                                              const float* __restrict__ res,
                                              float* __restrict__ C,
                                              int M_, int K_, int Nn) {
  __shared__ float As[16][65];
  __shared__ float Bs[16][65];
  const int t = threadIdx.x;
  const int bm = blockIdx.x * 64, bn = blockIdx.y * 64;
  const int tr = t >> 4, tc = t & 15;
  const int ar = t >> 2, ac = (t & 3) * 4;
  const int br = t >> 4, bc = (t & 15) * 4;
  float acc[4][4] = {};
  for (int k0 = 0; k0 < K_; k0 += 16) {
    float4 av = *(const float4*)(A + (size_t)(bm + ar) * K_ + k0 + ac);
    As[ac + 0][ar] = av.x; As[ac + 1][ar] = av.y;
    As[ac + 2][ar] = av.z; As[ac + 3][ar] = av.w;
    float4 bv = *(const float4*)(W + (size_t)(k0 + br) * Nn + bn + bc);
    Bs[br][bc + 0] = bv.x; Bs[br][bc + 1] = bv.y;
    Bs[br][bc + 2] = bv.z; Bs[br][bc + 3] = bv.w;
    __syncthreads();
#pragma unroll
    for (int kk = 0; kk < 16; kk++) {
      float a[4], b[4];
#pragma unroll
      for (int i = 0; i < 4; i++) a[i] = As[kk][tr * 4 + i];
#pragma unroll
      for (int j = 0; j < 4; j++) b[j] = Bs[kk][tc * 4 + j];
#pragma unroll
      for (int i = 0; i < 4; i++)
#pragma unroll
        for (int j = 0; j < 4; j++) acc[i][j] += a[i] * b[j];
    }
    __syncthreads();
  }
#pragma unroll
  for (int i = 0; i < 4; i++) {
    const int row = bm + tr * 4 + i;
#pragma unroll
    for (int j = 0; j < 4; j++) {
      const int col = bn + tc * 4 + j;
      float vv = acc[i][j] + bias[col];
      if (RELU) vv = fmaxf(vv, 0.f);
      if (RES) vv += res[(size_t)row * Nn + col];
      C[(size_t)row * Nn + col] = vv;
    }
  }
}

// ---------------------------------------------------------------------------
// RoPE (layer 0 only), in place on q and k. One thread per (b,n,pair).
__global__ __launch_bounds__(256) void rope_k(float* __restrict__ q,
                                              float* __restrict__ kk,
                                              const float* __restrict__ pos) {
  const int idx = blockIdx.x * 256 + threadIdx.x;
  if (idx >= BB * NN * (DIM / 2)) return;
  const int p = idx & 63;       // pair index 0..63
  const int bn = idx >> 6;
  const float coord = (p < 32) ? pos[(size_t)bn * 2] : pos[(size_t)bn * 2 + 1];
  const int f = p & 31;         // frequency index
  const float ang = coord * (3.14159265358979323846f * (float)(f + 1)); // 2*pi*(f+1)/PERIOD
  const float sn = sinf(ang), cs = cosf(ang);
  const size_t base = (size_t)bn * DIM + 2 * p;
  float a0 = q[base], a1 = q[base + 1];
  q[base] = cs * a0 - sn * a1;
  q[base + 1] = cs * a1 + sn * a0;
  float b0 = kk[base], b1 = kk[base + 1];
  kk[base] = cs * b0 - sn * b1;
  kk[base + 1] = cs * b1 + sn * b0;
}

// ---------------------------------------------------------------------------
// Flash-style masked attention, fp32.
// grid (N/32, B*H) x 256 threads. TQ=32 query rows, TK=64 key rows per tile.
__global__ __launch_bounds__(256) void attn_k(const float* __restrict__ q,
                                              const float* __restrict__ k,
                                              const float* __restrict__ v,
                                              const float* __restrict__ pos,
                                              float* __restrict__ o) {
  const int bh = blockIdx.y, b = bh >> 2, h = bh & 3;
  const int q0 = blockIdx.x * 32;
  __shared__ alignas(16) float qs[32][36];
  __shared__ alignas(16) float ks[64][36];
  __shared__ alignas(16) float vs[64][36];
  __shared__ alignas(16) float st[32][68];
  __shared__ float pqx[32], pqy[32], pkx[64], pky[64];
  __shared__ float mrow[32], lrow[32], fac[32];
  const int t = threadIdx.x;
  const float* qp = q + (size_t)b * NN * DIM + h * HD;
  const float* kp = k + (size_t)b * NN * DIM + h * HD;
  const float* vp = v + (size_t)b * NN * DIM + h * HD;

  for (int idx = t; idx < 32 * HD; idx += 256) {
    int r = idx >> 5, c = idx & 31;
    qs[r][c] = qp[(size_t)(q0 + r) * DIM + c];
  }
  if (t < 32) {
    pqx[t] = pos[((size_t)b * NN + q0 + t) * 2];
    pqy[t] = pos[((size_t)b * NN + q0 + t) * 2 + 1];
    mrow[t] = -1e30f;
    lrow[t] = 0.f;
  }
  float acc0 = 0.f, acc1 = 0.f, acc2 = 0.f, acc3 = 0.f;
  const int j = t & 63, ib = t >> 6;   // QK^T mapping
  const int d = t & 31, rg = t >> 5;   // PV mapping
  __syncthreads();

  for (int k0 = 0; k0 < NN; k0 += 64) {
    for (int idx = t; idx < 64 * HD; idx += 256) {
      int r = idx >> 5, c = idx & 31;
      ks[r][c] = kp[(size_t)(k0 + r) * DIM + c];
      vs[r][c] = vp[(size_t)(k0 + r) * DIM + c];
    }
    if (t < 64) {
      pkx[t] = pos[((size_t)b * NN + k0 + t) * 2];
      pky[t] = pos[((size_t)b * NN + k0 + t) * 2 + 1];
    }
    __syncthreads();

    // --- QK^T: each thread computes 8 scores (i = ib+4a, fixed j) ---
    float4 kr[8];
#pragma unroll
    for (int u = 0; u < 8; u++) kr[u] = *(const float4*)&ks[j][4 * u];
    const float kx = pkx[j], ky = pky[j];
#pragma unroll
    for (int a = 0; a < 8; a++) {
      const int i = ib + 4 * a;
      float s = 0.f;
#pragma unroll
      for (int u = 0; u < 8; u++) {
        float4 qv = *(const float4*)&qs[i][4 * u];
        s += qv.x * kr[u].x + qv.y * kr[u].y + qv.z * kr[u].z + qv.w * kr[u].w;
      }
      const float dx = pqx[i] - kx, dy = pqy[i] - ky;
      st[i][j] = (dx * dx + dy * dy <= R2) ? s * SCALE : -1e30f;
    }
    __syncthreads();

    // --- online softmax update: 8 threads per row ---
    {
      const int r = t >> 3, jo = (t & 7) * 8;
      const float m_old = mrow[r];
      float tm = -1e30f;
#pragma unroll
      for (int u = 0; u < 8; u++) tm = fmaxf(tm, st[r][jo + u]);
#pragma unroll
      for (int off = 1; off < 8; off <<= 1) tm = fmaxf(tm, __shfl_xor(tm, off, 64));
      const float nm = fmaxf(m_old, tm);
      const float f = expf(m_old - nm);
      float sum = 0.f;
#pragma unroll
      for (int u = 0; u < 8; u++) {
        float p = expf(st[r][jo + u] - nm);
        st[r][jo + u] = p;
        sum += p;
      }
#pragma unroll
      for (int off = 1; off < 8; off <<= 1) sum += __shfl_xor(sum, off, 64);
      if ((t & 7) == 0) {
        mrow[r] = nm;
        lrow[r] = lrow[r] * f + sum;
        fac[r] = f;
      }
    }
    __syncthreads();

    // --- rescale + PV: thread owns (d, rows rg+8a) ---
    {
      acc0 *= fac[rg];
      acc1 *= fac[rg + 8];
      acc2 *= fac[rg + 16];
      acc3 *= fac[rg + 24];
#pragma unroll
      for (int jc = 0; jc < 64; jc += 4) {
        float s0[4], s1[4], s2[4], s3[4];
        *(float4*)s0 = *(const float4*)&st[rg][jc];
        *(float4*)s1 = *(const float4*)&st[rg + 8][jc];
        *(float4*)s2 = *(const float4*)&st[rg + 16][jc];
        *(float4*)s3 = *(const float4*)&st[rg + 24][jc];
#pragma unroll
        for (int u = 0; u < 4; u++) {
          const float vv = vs[jc + u][d];
          acc0 += s0[u] * vv;
          acc1 += s1[u] * vv;
          acc2 += s2[u] * vv;
          acc3 += s3[u] * vv;
        }
      }
    }
    __syncthreads();
  }

  float* op = o + (size_t)b * NN * DIM + h * HD;
  op[(size_t)(q0 + rg) * DIM + d] = acc0 / lrow[rg];
  op[(size_t)(q0 + rg + 8) * DIM + d] = acc1 / lrow[rg + 8];
  op[(size_t)(q0 + rg + 16) * DIM + d] = acc2 / lrow[rg + 16];
  op[(size_t)(q0 + rg + 24) * DIM + d] = acc3 / lrow[rg + 24];
}

// ---------------------------------------------------------------------------
extern "C" void kernel_launch(void* const* d_in, const int* in_sizes, int n_in,
                              void* d_out, int out_size, void* d_ws, size_t ws_size,
                              hipStream_t stream) {
  const float* x = (const float*)d_in[0];
  const float* pos = (const float*)d_in[1];
  const float* Wq_w = (const float*)d_in[2];
  const float* Wq_b = (const float*)d_in[3];
  const float* Wk_w = (const float*)d_in[4];
  const float* Wk_b = (const float*)d_in[5];
  const float* Wv_w = (const float*)d_in[6];
  const float* Wv_b = (const float*)d_in[7];
  const float* Wo_w = (const float*)d_in[8];
  const float* Wo_b = (const float*)d_in[9];
  const float* n1_g = (const float*)d_in[10];
  const float* n1_b = (const float*)d_in[11];
  const float* n2_g = (const float*)d_in[12];
  const float* n2_b = (const float*)d_in[13];
  const float* l1_w = (const float*)d_in[14];
  const float* l1_b = (const float*)d_in[15];
  const float* l2_w = (const float*)d_in[16];
  const float* l2_b = (const float*)d_in[17];

  float* out = (float*)d_out;
  float* ws = (float*)d_ws;
  const size_t MN = (size_t)MROWS * DIM;  // 1048576 elements
  // workspace layout (floats): needs (7*MN + 256)*4 ≈ 29.4 MB
  float* xn = ws;
  float* qb = ws + MN;
  float* kb = ws + 2 * MN;
  float* vb = ws + 3 * MN;
  float* ob = ws + 4 * MN;
  float* hb = ws + 5 * MN;   // 2*MN for FFN hidden
  float* sums = ws + 7 * MN;

  hipMemcpyAsync(out, x, MN * sizeof(float), hipMemcpyDeviceToDevice, stream);

  for (int l = 0; l < LYR; l++) {
    // --- attention block ---
    hipMemsetAsync(sums, 0, 256 * sizeof(float), stream);
    bn_stats_k<<<64, 256, 0, stream>>>(out, sums);
    bn_apply_k<<<4096, 256, 0, stream>>>(out, sums, n1_g + l * DIM, n1_b + l * DIM, xn);

    gemm_k<false, false><<<dim3(128, 2), 256, 0, stream>>>(
        xn, Wq_w + (size_t)l * DIM * DIM, Wq_b + l * DIM, nullptr, qb, MROWS, DIM, DIM);
    gemm_k<false, false><<<dim3(128, 2), 256, 0, stream>>>(
        xn, Wk_w + (size_t)l * DIM * DIM, Wk_b + l * DIM, nullptr, kb, MROWS, DIM, DIM);
    gemm_k<false, false><<<dim3(128, 2), 256, 0, stream>>>(
        xn, Wv_w + (size_t)l * DIM * DIM, Wv_b + l * DIM, nullptr, vb, MROWS, DIM, DIM);

    if (l == 0) rope_k<<<2048, 256, 0, stream>>>(qb, kb, pos);

    attn_k<<<dim3(NN / 32, BB * NH), 256, 0, stream>>>(qb, kb, vb, pos, ob);

    gemm_k<false, true><<<dim3(128, 2), 256, 0, stream>>>(
        ob, Wo_w + (size_t)l * DIM * DIM, Wo_b + l * DIM, out, out, MROWS, DIM, DIM);

    // --- FFN block ---
    hipMemsetAsync(sums, 0, 256 * sizeof(float), stream);
    bn_stats_k<<<64, 256, 0, stream>>>(out, sums);
    bn_apply_k<<<4096, 256, 0, stream>>>(out, sums, n2_g + l * DIM, n2_b + l * DIM, xn);

    gemm_k<true, false><<<dim3(128, 4), 256, 0, stream>>>(
        xn, l1_w + (size_t)l * DIM * 2 * DIM, l1_b + l * 2 * DIM, nullptr, hb, MROWS, DIM, 2 * DIM);
    gemm_k<false, true><<<dim3(128, 2), 256, 0, stream>>>(
        hb, l2_w + (size_t)l * 2 * DIM * DIM, l2_b + l * DIM, out, out, MROWS, 2 * DIM, DIM);
  }
}

// Round 2
// 696.263 us; speedup vs baseline: 2.3510x; 2.3510x over previous
//
#include <hip/hip_runtime.h>
#include <hip/hip_bf16.h>
#include <math.h>

// Problem constants
#define LYR 2
#define DIM 128
#define NH 4
#define HD 32
#define BB 2
#define NN 4096
#define MROWS (BB * NN)          // 8192
#define SCALE 0.17677669529663687f   // 1/sqrt(32)
#define R2 0.0625f               // (WINDOW/2)^2
#define BN_EPS 1e-5f

typedef __attribute__((ext_vector_type(4))) float f32x4;
typedef __attribute__((ext_vector_type(8))) short bf16x8;
typedef __attribute__((ext_vector_type(4))) short bf16x4;

static __device__ inline unsigned short f2bf(float f) {
  union { float f; unsigned u; } v; v.f = f;
  unsigned r = v.u + 0x7FFFu + ((v.u >> 16) & 1u);   // round-to-nearest-even
  return (unsigned short)(r >> 16);
}

// ---------------------------------------------------------------------------
// BatchNorm: partial sums (sum, sumsq) per feature via atomics
__global__ __launch_bounds__(256) void bn_stats_k(const float* __restrict__ x,
                                                  float* __restrict__ sums) {
  __shared__ float ss[256], sq[256];
  const int t = threadIdx.x;
  const size_t base = (size_t)blockIdx.x * (128 * DIM);
  float s = 0.f, qq = 0.f;
  for (int idx = t; idx < 128 * DIM; idx += 256) {
    float vv = x[base + idx];
    s += vv; qq += vv * vv;
  }
  ss[t] = s; sq[t] = qq;
  __syncthreads();
  if (t < 128) {
    float s2 = ss[t] + ss[t + 128];
    float q2 = sq[t] + sq[t + 128];
    atomicAdd(&sums[t], s2);
    atomicAdd(&sums[128 + t], q2);
  }
}

__global__ __launch_bounds__(256) void bn_apply_k(const float* __restrict__ x,
                                                  const float* __restrict__ sums,
                                                  const float* __restrict__ g,
                                                  const float* __restrict__ bta,
                                                  float* __restrict__ y) {
  const int idx = blockIdx.x * 256 + threadIdx.x;
  const int dd = idx & (DIM - 1);
  const float inv = 1.0f / (float)MROWS;
  float mu = sums[dd] * inv;
  float var = sums[128 + dd] * inv - mu * mu;
  float rs = rsqrtf(var + BN_EPS);
  y[idx] = (x[idx] - mu) * rs * g[dd] + bta[dd];
}

// ---------------------------------------------------------------------------
// fp32 GEMM: C[M,Nn] = A[M,K] @ W[K,Nn] + bias (+res) (ReLU optional)
template <bool RELU, bool RES>
__global__ __launch_bounds__(256) void gemm_k(const float* __restrict__ A,
                                              const float* __restrict__ W,
                                              const float* __restrict__ bias,
                                              const float* __restrict__ res,
                                              float* __restrict__ C,
                                              int M_, int K_, int Nn) {
  __shared__ float As[16][65];
  __shared__ float Bs[16][65];
  const int t = threadIdx.x;
  const int bm = blockIdx.x * 64, bn = blockIdx.y * 64;
  const int tr = t >> 4, tc = t & 15;
  const int ar = t >> 2, ac = (t & 3) * 4;
  const int br = t >> 4, bc = (t & 15) * 4;
  float acc[4][4] = {};
  for (int k0 = 0; k0 < K_; k0 += 16) {
    float4 av = *(const float4*)(A + (size_t)(bm + ar) * K_ + k0 + ac);
    As[ac + 0][ar] = av.x; As[ac + 1][ar] = av.y;
    As[ac + 2][ar] = av.z; As[ac + 3][ar] = av.w;
    float4 bv = *(const float4*)(W + (size_t)(k0 + br) * Nn + bn + bc);
    Bs[br][bc + 0] = bv.x; Bs[br][bc + 1] = bv.y;
    Bs[br][bc + 2] = bv.z; Bs[br][bc + 3] = bv.w;
    __syncthreads();
#pragma unroll
    for (int kk = 0; kk < 16; kk++) {
      float a[4], b[4];
#pragma unroll
      for (int i = 0; i < 4; i++) a[i] = As[kk][tr * 4 + i];
#pragma unroll
      for (int j = 0; j < 4; j++) b[j] = Bs[kk][tc * 4 + j];
#pragma unroll
      for (int i = 0; i < 4; i++)
#pragma unroll
        for (int j = 0; j < 4; j++) acc[i][j] += a[i] * b[j];
    }
    __syncthreads();
  }
#pragma unroll
  for (int i = 0; i < 4; i++) {
    const int row = bm + tr * 4 + i;
#pragma unroll
    for (int j = 0; j < 4; j++) {
      const int col = bn + tc * 4 + j;
      float vv = acc[i][j] + bias[col];
      if (RELU) vv = fmaxf(vv, 0.f);
      if (RES) vv += res[(size_t)row * Nn + col];
      C[(size_t)row * Nn + col] = vv;
    }
  }
}

// ---------------------------------------------------------------------------
// RoPE (layer 0 only), in place on q and k.
__global__ __launch_bounds__(256) void rope_k(float* __restrict__ q,
                                              float* __restrict__ kk,
                                              const float* __restrict__ pos) {
  const int idx = blockIdx.x * 256 + threadIdx.x;
  if (idx >= BB * NN * (DIM / 2)) return;
  const int p = idx & 63;
  const int bn = idx >> 6;
  const float coord = (p < 32) ? pos[(size_t)bn * 2] : pos[(size_t)bn * 2 + 1];
  const int f = p & 31;
  const float ang = coord * (3.14159265358979323846f * (float)(f + 1));
  const float sn = sinf(ang), cs = cosf(ang);
  const size_t base = (size_t)bn * DIM + 2 * p;
  float a0 = q[base], a1 = q[base + 1];
  q[base] = cs * a0 - sn * a1;
  q[base + 1] = cs * a1 + sn * a0;
  float b0 = kk[base], b1 = kk[base + 1];
  kk[base] = cs * b0 - sn * b1;
  kk[base + 1] = cs * b1 + sn * b0;
}

// ---------------------------------------------------------------------------
// MFMA flash attention (bf16 inputs, fp32 accumulate).
// grid (N/64, B*H) x 256 threads (4 waves). Block = 64 Q rows, wave = 16 rows.
// KV tile = 64. Swapped QK^T: S^T = mfma(K_frag, Q_frag) -> lane col = query.
__global__ __launch_bounds__(256) void attn_mfma_k(const float* __restrict__ q,
                                                   const float* __restrict__ k,
                                                   const float* __restrict__ v,
                                                   const float* __restrict__ pos,
                                                   float* __restrict__ o) {
  const int bh = blockIdx.y, b = bh >> 2, h = bh & 3;
  const int q0 = blockIdx.x * 64;
  __shared__ short qs_s[64 * 40];     // Q tile bf16, row stride 40
  __shared__ short ks_s[64 * 40];     // K tile bf16, row stride 40
  __shared__ short vt_s[32 * 72];     // V^T tile bf16 [d][j], row stride 72
  __shared__ short ps_s[4 * 16 * 72]; // per-wave P [i][j], row stride 72
  __shared__ float pqx[64], pqy[64], pkx[64], pky[64];
  __shared__ float fac_s[64], lr_s[64];  // per-wave 16-entry blocks
  const int t = threadIdx.x;
  const int w = t >> 6, lane = t & 63, g = lane >> 4, i16 = lane & 15;
  const int js = t >> 2, dq = t & 3;   // staging: row, 8-float chunk
  const float* qp = q + (size_t)b * NN * DIM + h * HD;
  const float* kp = k + (size_t)b * NN * DIM + h * HD;
  const float* vp = v + (size_t)b * NN * DIM + h * HD;

  // stage Q (bf16) + q positions
  {
    const float* src = qp + (size_t)(q0 + js) * DIM + dq * 8;
    float4 a = *(const float4*)src, bv = *(const float4*)(src + 4);
    bf16x8 t8;
    t8[0] = f2bf(a.x);  t8[1] = f2bf(a.y);  t8[2] = f2bf(a.z);  t8[3] = f2bf(a.w);
    t8[4] = f2bf(bv.x); t8[5] = f2bf(bv.y); t8[6] = f2bf(bv.z); t8[7] = f2bf(bv.w);
    *(bf16x8*)&qs_s[js * 40 + dq * 8] = t8;
    if (t < 64) {
      float2 pp = *(const float2*)&pos[((size_t)b * NN + q0 + t) * 2];
      pqx[t] = pp.x; pqy[t] = pp.y;
    }
  }
  __syncthreads();
  const bf16x8 qf = *(const bf16x8*)&qs_s[(16 * w + i16) * 40 + 8 * g];
  const float qx = pqx[16 * w + i16], qy = pqy[16 * w + i16];
  f32x4 acc0 = {0.f, 0.f, 0.f, 0.f}, acc1 = {0.f, 0.f, 0.f, 0.f};
  const f32x4 zf = {0.f, 0.f, 0.f, 0.f};
  float m_run = -1e30f, l_run = 0.f;

  for (int k0 = 0; k0 < NN; k0 += 64) {
    __syncthreads();   // protect previous tile's LDS readers
    // stage K tile
    {
      const float* src = kp + (size_t)(k0 + js) * DIM + dq * 8;
      float4 a = *(const float4*)src, bv = *(const float4*)(src + 4);
      bf16x8 t8;
      t8[0] = f2bf(a.x);  t8[1] = f2bf(a.y);  t8[2] = f2bf(a.z);  t8[3] = f2bf(a.w);
      t8[4] = f2bf(bv.x); t8[5] = f2bf(bv.y); t8[6] = f2bf(bv.z); t8[7] = f2bf(bv.w);
      *(bf16x8*)&ks_s[js * 40 + dq * 8] = t8;
    }
    // stage V transposed: vt[d][j]
    {
      const float* src = vp + (size_t)(k0 + js) * DIM + dq * 8;
      float4 a = *(const float4*)src, bv = *(const float4*)(src + 4);
      unsigned short e[8];
      e[0] = f2bf(a.x);  e[1] = f2bf(a.y);  e[2] = f2bf(a.z);  e[3] = f2bf(a.w);
      e[4] = f2bf(bv.x); e[5] = f2bf(bv.y); e[6] = f2bf(bv.z); e[7] = f2bf(bv.w);
#pragma unroll
      for (int m = 0; m < 8; m++) {
        int ue = (m + dq) & 7;  // rotate to spread banks
        vt_s[(dq * 8 + ue) * 72 + js] = (short)e[ue];
      }
      if (t < 64) {
        float2 pp = *(const float2*)&pos[((size_t)b * NN + k0 + t) * 2];
        pkx[t] = pp.x; pky[t] = pp.y;
      }
    }
    __syncthreads();

    // --- QK^T (swapped): sx[jt] rows j = 16*jt + 4g + r, col = query i16 ---
    f32x4 sx[4];
#pragma unroll
    for (int jt = 0; jt < 4; jt++) {
      bf16x8 kf = *(const bf16x8*)&ks_s[(16 * jt + i16) * 40 + 8 * g];
      sx[jt] = __builtin_amdgcn_mfma_f32_16x16x32_bf16(kf, qf, zf, 0, 0, 0);
    }

    // --- mask + online softmax (all in registers) ---
    float pv[16];
    float tmax = -1e30f;
#pragma unroll
    for (int jt = 0; jt < 4; jt++) {
      float4 kx4 = *(const float4*)&pkx[16 * jt + 4 * g];
      float4 ky4 = *(const float4*)&pky[16 * jt + 4 * g];
      const float kxa[4] = {kx4.x, kx4.y, kx4.z, kx4.w};
      const float kya[4] = {ky4.x, ky4.y, ky4.z, ky4.w};
#pragma unroll
      for (int r = 0; r < 4; r++) {
        float dx = qx - kxa[r], dy = qy - kya[r];
        float val = (dx * dx + dy * dy <= R2) ? sx[jt][r] * SCALE : -1e30f;
        pv[jt * 4 + r] = val;
        tmax = fmaxf(tmax, val);
      }
    }
    tmax = fmaxf(tmax, __shfl_xor(tmax, 16, 64));
    tmax = fmaxf(tmax, __shfl_xor(tmax, 32, 64));
    const float mnew = fmaxf(m_run, tmax);
    const float f = __expf(m_run - mnew);
    float tsum = 0.f;
    unsigned short pb[16];
#pragma unroll
    for (int u = 0; u < 16; u++) {
      float p = __expf(pv[u] - mnew);
      tsum += p;
      pb[u] = f2bf(p);
    }
    tsum += __shfl_xor(tsum, 16, 64);
    tsum += __shfl_xor(tsum, 32, 64);
    l_run = l_run * f + tsum;
    m_run = mnew;

    // write P rows: ps[i16][16*jt + 4g .. +4]
#pragma unroll
    for (int jt = 0; jt < 4; jt++) {
      bf16x4 pw;
      pw[0] = (short)pb[jt * 4 + 0]; pw[1] = (short)pb[jt * 4 + 1];
      pw[2] = (short)pb[jt * 4 + 2]; pw[3] = (short)pb[jt * 4 + 3];
      *(bf16x4*)&ps_s[w * 1152 + i16 * 72 + 16 * jt + 4 * g] = pw;
    }
    // rescale factor for output rows i' = 4g + r (per-wave LDS exchange)
    if (lane < 16) fac_s[w * 16 + lane] = f;
    float4 f4 = *(const float4*)&fac_s[w * 16 + 4 * g];
    acc0[0] *= f4.x; acc0[1] *= f4.y; acc0[2] *= f4.z; acc0[3] *= f4.w;
    acc1[0] *= f4.x; acc1[1] *= f4.y; acc1[2] *= f4.z; acc1[3] *= f4.w;

    // --- PV: O[i][d] += P[i][j] V[j][d], j contraction in 2 steps ---
#pragma unroll
    for (int ks2 = 0; ks2 < 2; ks2++) {
      bf16x8 pf = *(const bf16x8*)&ps_s[w * 1152 + i16 * 72 + 8 * g + 32 * ks2];
      bf16x8 vf0 = *(const bf16x8*)&vt_s[i16 * 72 + 8 * g + 32 * ks2];
      bf16x8 vf1 = *(const bf16x8*)&vt_s[(16 + i16) * 72 + 8 * g + 32 * ks2];
      acc0 = __builtin_amdgcn_mfma_f32_16x16x32_bf16(pf, vf0, acc0, 0, 0, 0);
      acc1 = __builtin_amdgcn_mfma_f32_16x16x32_bf16(pf, vf1, acc1, 0, 0, 0);
    }
  }

  // epilogue: divide by l, store
  if (lane < 16) lr_s[w * 16 + lane] = l_run;
  float4 l4 = *(const float4*)&lr_s[w * 16 + 4 * g];
  const float la[4] = {l4.x, l4.y, l4.z, l4.w};
  float* op = o + (size_t)b * NN * DIM + h * HD;
#pragma unroll
  for (int r = 0; r < 4; r++) {
    const float inv = 1.0f / la[r];
    const size_t row = (size_t)(q0 + 16 * w + 4 * g + r) * DIM;
    op[row + i16] = acc0[r] * inv;
    op[row + 16 + i16] = acc1[r] * inv;
  }
}

// ---------------------------------------------------------------------------
extern "C" void kernel_launch(void* const* d_in, const int* in_sizes, int n_in,
                              void* d_out, int out_size, void* d_ws, size_t ws_size,
                              hipStream_t stream) {
  const float* x = (const float*)d_in[0];
  const float* pos = (const float*)d_in[1];
  const float* Wq_w = (const float*)d_in[2];
  const float* Wq_b = (const float*)d_in[3];
  const float* Wk_w = (const float*)d_in[4];
  const float* Wk_b = (const float*)d_in[5];
  const float* Wv_w = (const float*)d_in[6];
  const float* Wv_b = (const float*)d_in[7];
  const float* Wo_w = (const float*)d_in[8];
  const float* Wo_b = (const float*)d_in[9];
  const float* n1_g = (const float*)d_in[10];
  const float* n1_b = (const float*)d_in[11];
  const float* n2_g = (const float*)d_in[12];
  const float* n2_b = (const float*)d_in[13];
  const float* l1_w = (const float*)d_in[14];
  const float* l1_b = (const float*)d_in[15];
  const float* l2_w = (const float*)d_in[16];
  const float* l2_b = (const float*)d_in[17];

  float* out = (float*)d_out;
  float* ws = (float*)d_ws;
  const size_t MN = (size_t)MROWS * DIM;
  float* xn = ws;
  float* qb = ws + MN;
  float* kb = ws + 2 * MN;
  float* vb = ws + 3 * MN;
  float* ob = ws + 4 * MN;
  float* hb = ws + 5 * MN;
  float* sums = ws + 7 * MN;

  hipMemcpyAsync(out, x, MN * sizeof(float), hipMemcpyDeviceToDevice, stream);

  for (int l = 0; l < LYR; l++) {
    // --- attention block ---
    hipMemsetAsync(sums, 0, 256 * sizeof(float), stream);
    bn_stats_k<<<64, 256, 0, stream>>>(out, sums);
    bn_apply_k<<<4096, 256, 0, stream>>>(out, sums, n1_g + l * DIM, n1_b + l * DIM, xn);

    gemm_k<false, false><<<dim3(128, 2), 256, 0, stream>>>(
        xn, Wq_w + (size_t)l * DIM * DIM, Wq_b + l * DIM, nullptr, qb, MROWS, DIM, DIM);
    gemm_k<false, false><<<dim3(128, 2), 256, 0, stream>>>(
        xn, Wk_w + (size_t)l * DIM * DIM, Wk_b + l * DIM, nullptr, kb, MROWS, DIM, DIM);
    gemm_k<false, false><<<dim3(128, 2), 256, 0, stream>>>(
        xn, Wv_w + (size_t)l * DIM * DIM, Wv_b + l * DIM, nullptr, vb, MROWS, DIM, DIM);

    if (l == 0) rope_k<<<2048, 256, 0, stream>>>(qb, kb, pos);

    attn_mfma_k<<<dim3(NN / 64, BB * NH), 256, 0, stream>>>(qb, kb, vb, pos, ob);

    gemm_k<false, true><<<dim3(128, 2), 256, 0, stream>>>(
        ob, Wo_w + (size_t)l * DIM * DIM, Wo_b + l * DIM, out, out, MROWS, DIM, DIM);

    // --- FFN block ---
    hipMemsetAsync(sums, 0, 256 * sizeof(float), stream);
    bn_stats_k<<<64, 256, 0, stream>>>(out, sums);
    bn_apply_k<<<4096, 256, 0, stream>>>(out, sums, n2_g + l * DIM, n2_b + l * DIM, xn);

    gemm_k<true, false><<<dim3(128, 4), 256, 0, stream>>>(
        xn, l1_w + (size_t)l * DIM * 2 * DIM, l1_b + l * 2 * DIM, nullptr, hb, MROWS, DIM, 2 * DIM);
    gemm_k<false, true><<<dim3(128, 2), 256, 0, stream>>>(
        hb, l2_w + (size_t)l * 2 * DIM * DIM, l2_b + l * DIM, out, out, MROWS, 2 * DIM, DIM);
  }
}

// Round 3
// 417.286 us; speedup vs baseline: 3.9228x; 1.6686x over previous
//
#include <hip/hip_runtime.h>
#include <hip/hip_bf16.h>
#include <math.h>

// Problem constants
#define LYR 2
#define DIM 128
#define NH 4
#define HD 32
#define BB 2
#define NN 4096
#define MROWS (BB * NN)          // 8192
#define SCALE 0.17677669529663687f   // 1/sqrt(32)
#define R2 0.0625f               // (WINDOW/2)^2
#define BN_EPS 1e-5f

typedef __attribute__((ext_vector_type(4))) float f32x4;
typedef __attribute__((ext_vector_type(8))) short bf16x8;
typedef __attribute__((ext_vector_type(4))) short bf16x4;

static __device__ inline unsigned short f2bf(float f) {
  union { float f; unsigned u; } v; v.f = f;
  unsigned r = v.u + 0x7FFFu + ((v.u >> 16) & 1u);   // round-to-nearest-even
  return (unsigned short)(r >> 16);
}
static __device__ inline float bf2f(short s) {
  union { unsigned u; float f; } v;
  v.u = ((unsigned)(unsigned short)s) << 16;
  return v.f;
}

// ---------------------------------------------------------------------------
// Weight prep: fp32 W[K][N] -> bf16 W^T[N][K], all matrices, both layers.
// grid 256 blocks; one block = one 32x32 tile.
__global__ __launch_bounds__(256) void wprep_k(const float* __restrict__ Wq,
                                               const float* __restrict__ Wk,
                                               const float* __restrict__ Wv,
                                               const float* __restrict__ Wo,
                                               const float* __restrict__ L1,
                                               const float* __restrict__ L2,
                                               short* __restrict__ wT) {
  const int id = blockIdx.x;
  const int l = id >> 7, r = id & 127;
  const size_t lbase = (size_t)l * 131072;
  const float* src; short* dst; int K, N, tk, tn;
  if (r < 64) {
    const int m = r >> 4, tile = r & 15;
    if (m == 0)      src = Wq + (size_t)l * 16384;
    else if (m == 1) src = Wk + (size_t)l * 16384;
    else if (m == 2) src = Wv + (size_t)l * 16384;
    else             src = Wo + (size_t)l * 16384;
    dst = wT + lbase + (size_t)m * 16384;
    K = 128; N = 128; tk = tile >> 2; tn = tile & 3;
  } else if (r < 96) {
    const int tile = r - 64;
    src = L1 + (size_t)l * 32768; dst = wT + lbase + 65536;
    K = 128; N = 256; tk = tile >> 3; tn = tile & 7;
  } else {
    const int tile = r - 96;
    src = L2 + (size_t)l * 32768; dst = wT + lbase + 98304;
    K = 256; N = 128; tk = tile >> 2; tn = tile & 3;
  }
  __shared__ float tl[32][33];
  const int t = threadIdx.x;
  const int rr = t >> 3, c4 = (t & 7) * 4;
  float4 vv = *(const float4*)(src + (size_t)(tk * 32 + rr) * N + tn * 32 + c4);
  tl[rr][c4 + 0] = vv.x; tl[rr][c4 + 1] = vv.y;
  tl[rr][c4 + 2] = vv.z; tl[rr][c4 + 3] = vv.w;
  __syncthreads();
  bf16x4 o4;
  o4[0] = (short)f2bf(tl[c4 + 0][rr]);
  o4[1] = (short)f2bf(tl[c4 + 1][rr]);
  o4[2] = (short)f2bf(tl[c4 + 2][rr]);
  o4[3] = (short)f2bf(tl[c4 + 3][rr]);
  *(bf16x4*)(dst + (size_t)(tn * 32 + rr) * K + tk * 32 + c4) = o4;
}

// ---------------------------------------------------------------------------
// BatchNorm stats: per-feature (sum, sumsq) via atomics. grid 256 x 256.
__global__ __launch_bounds__(256) void bn_stats_k(const float* __restrict__ x,
                                                  float* __restrict__ sums) {
  __shared__ float ss[8][128], sq[8][128];
  const int t = threadIdx.x;
  const int c4 = (t & 31) * 4, rg = t >> 5;
  const size_t base = (size_t)blockIdx.x * (32 * DIM);
  float s0 = 0.f, s1 = 0.f, s2 = 0.f, s3 = 0.f;
  float q0 = 0.f, q1 = 0.f, q2 = 0.f, q3 = 0.f;
  for (int r = rg; r < 32; r += 8) {
    float4 v = *(const float4*)&x[base + (size_t)r * DIM + c4];
    s0 += v.x; q0 += v.x * v.x;
    s1 += v.y; q1 += v.y * v.y;
    s2 += v.z; q2 += v.z * v.z;
    s3 += v.w; q3 += v.w * v.w;
  }
  ss[rg][c4 + 0] = s0; sq[rg][c4 + 0] = q0;
  ss[rg][c4 + 1] = s1; sq[rg][c4 + 1] = q1;
  ss[rg][c4 + 2] = s2; sq[rg][c4 + 2] = q2;
  ss[rg][c4 + 3] = s3; sq[rg][c4 + 3] = q3;
  __syncthreads();
  if (t < 128) {
    float S = 0.f, Q = 0.f;
#pragma unroll
    for (int r2 = 0; r2 < 8; r2++) { S += ss[r2][t]; Q += sq[r2][t]; }
    atomicAdd(&sums[t], S);
    atomicAdd(&sums[128 + t], Q);
  }
}

// BN apply -> bf16 output. grid 1024 x 256 (4 elems/thread).
__global__ __launch_bounds__(256) void bn_apply_k(const float* __restrict__ x,
                                                  const float* __restrict__ sums,
                                                  const float* __restrict__ g,
                                                  const float* __restrict__ bta,
                                                  short* __restrict__ y) {
  const int i4 = blockIdx.x * 256 + threadIdx.x;
  const int dd = (i4 * 4) & (DIM - 1);
  const float inv = 1.0f / (float)MROWS;
  float4 xv = *(const float4*)&x[(size_t)i4 * 4];
  float4 sm = *(const float4*)&sums[dd];
  float4 sq = *(const float4*)&sums[128 + dd];
  float4 gg = *(const float4*)&g[dd];
  float4 bb = *(const float4*)&bta[dd];
  float mu0 = sm.x * inv, mu1 = sm.y * inv, mu2 = sm.z * inv, mu3 = sm.w * inv;
  bf16x4 o;
  o[0] = (short)f2bf((xv.x - mu0) * rsqrtf(sq.x * inv - mu0 * mu0 + BN_EPS) * gg.x + bb.x);
  o[1] = (short)f2bf((xv.y - mu1) * rsqrtf(sq.y * inv - mu1 * mu1 + BN_EPS) * gg.y + bb.y);
  o[2] = (short)f2bf((xv.z - mu2) * rsqrtf(sq.z * inv - mu2 * mu2 + BN_EPS) * gg.z + bb.z);
  o[3] = (short)f2bf((xv.w - mu3) * rsqrtf(sq.w * inv - mu3 * mu3 + BN_EPS) * gg.w + bb.w);
  *(bf16x4*)&y[(size_t)i4 * 4] = o;
}

// ---------------------------------------------------------------------------
// bf16 MFMA GEMM: C[M][Nn] = A[M][K] @ W + bias, A bf16 row-major,
// WT bf16 [Nn][K] (pre-transposed). BM=BN=64, BK=64, 256 threads / 4 waves.
// MODE 0: fp32 out with residual add (Cf = acc + bias + res)
// MODE 1: bf16 row-major out (optional RELU)
// MODE 2: bf16 transposed head-major out (vt[bh][d][n]) for attention V
template <int MODE, bool RELU>
__global__ __launch_bounds__(256) void gemm_bf_k(const short* __restrict__ A,
                                                 const short* __restrict__ WT,
                                                 const float* __restrict__ bias,
                                                 const float* res,
                                                 float* Cf,
                                                 short* __restrict__ Cb,
                                                 int K, int Nn) {
  __shared__ short a_s[64 * 80];
  __shared__ short w_s[64 * 80];
  const int t = threadIdx.x, w = t >> 6, lane = t & 63, g = lane >> 4, i16 = lane & 15;
  const int bm = blockIdx.x * 64, bn = blockIdx.y * 64;
  const int sr = t >> 2, sc = (t & 3) * 8;
  f32x4 acc[4];
#pragma unroll
  for (int ct = 0; ct < 4; ct++) acc[ct] = (f32x4){0.f, 0.f, 0.f, 0.f};
  for (int k0 = 0; k0 < K; k0 += 64) {
    __syncthreads();
    *(bf16x8*)&a_s[sr * 80 + sc]      = *(const bf16x8*)(A + (size_t)(bm + sr) * K + k0 + sc);
    *(bf16x8*)&a_s[sr * 80 + sc + 32] = *(const bf16x8*)(A + (size_t)(bm + sr) * K + k0 + sc + 32);
    *(bf16x8*)&w_s[sr * 80 + sc]      = *(const bf16x8*)(WT + (size_t)(bn + sr) * K + k0 + sc);
    *(bf16x8*)&w_s[sr * 80 + sc + 32] = *(const bf16x8*)(WT + (size_t)(bn + sr) * K + k0 + sc + 32);
    __syncthreads();
#pragma unroll
    for (int ks = 0; ks < 2; ks++) {
      bf16x8 af = *(const bf16x8*)&a_s[(16 * w + i16) * 80 + ks * 32 + 8 * g];
#pragma unroll
      for (int ct = 0; ct < 4; ct++) {
        bf16x8 wf = *(const bf16x8*)&w_s[(ct * 16 + i16) * 80 + ks * 32 + 8 * g];
        acc[ct] = __builtin_amdgcn_mfma_f32_16x16x32_bf16(af, wf, acc[ct], 0, 0, 0);
      }
    }
  }
#pragma unroll
  for (int ct = 0; ct < 4; ct++) {
    const int col = bn + ct * 16 + i16;
    const float bv = bias[col];
    if (MODE == 2) {
      const int row0 = bm + 16 * w + 4 * g;
      const int b_ = row0 >> 12, n_ = row0 & (NN - 1);
      const int hh = col >> 5, dd = col & 31;
      bf16x4 o4;
#pragma unroll
      for (int r = 0; r < 4; r++) o4[r] = (short)f2bf(acc[ct][r] + bv);
      *(bf16x4*)(Cb + ((size_t)(b_ * NH + hh) * HD + dd) * NN + n_) = o4;
    } else {
#pragma unroll
      for (int r = 0; r < 4; r++) {
        const int row = bm + 16 * w + 4 * g + r;
        float vv = acc[ct][r] + bv;
        if (RELU) vv = fmaxf(vv, 0.f);
        if (MODE == 0) Cf[(size_t)row * Nn + col] = vv + res[(size_t)row * Nn + col];
        else Cb[(size_t)row * Nn + col] = (short)f2bf(vv);
      }
    }
  }
}

// ---------------------------------------------------------------------------
// RoPE in place on bf16 q,k (layer 0). grid 128 x 256; thread = (row, head).
__global__ __launch_bounds__(256) void rope_bf_k(short* __restrict__ q,
                                                 short* __restrict__ kk,
                                                 const float* __restrict__ pos) {
  const int idx = blockIdx.x * 256 + threadIdx.x;   // 32768
  const int row = idx >> 2, hh = idx & 3;
  const float2 pp = *(const float2*)&pos[(size_t)row * 2];
  short* qp = q + (size_t)row * DIM + hh * HD;
  short* kp = kk + (size_t)row * DIM + hh * HD;
  bf16x8 qv[4], kv[4];
#pragma unroll
  for (int u = 0; u < 4; u++) {
    qv[u] = *(const bf16x8*)(qp + 8 * u);
    kv[u] = *(const bf16x8*)(kp + 8 * u);
  }
#pragma unroll
  for (int lp = 0; lp < 16; lp++) {
    const int p = hh * 16 + lp;
    const float coord = (p < 32) ? pp.x : pp.y;
    const int f = p & 31;
    float sn, cs;
    __sincosf(3.14159265358979323846f * (float)(f + 1) * coord, &sn, &cs);
    const int u = lp >> 2, e = (lp & 3) * 2;
    const float a0 = bf2f(qv[u][e]), a1 = bf2f(qv[u][e + 1]);
    qv[u][e]     = (short)f2bf(cs * a0 - sn * a1);
    qv[u][e + 1] = (short)f2bf(cs * a1 + sn * a0);
    const float b0 = bf2f(kv[u][e]), b1 = bf2f(kv[u][e + 1]);
    kv[u][e]     = (short)f2bf(cs * b0 - sn * b1);
    kv[u][e + 1] = (short)f2bf(cs * b1 + sn * b0);
  }
#pragma unroll
  for (int u = 0; u < 4; u++) {
    *(bf16x8*)(qp + 8 * u) = qv[u];
    *(bf16x8*)(kp + 8 * u) = kv[u];
  }
}

// ---------------------------------------------------------------------------
// MFMA flash attention, pre-converted bf16 inputs.
// q,k: bf16 [M][128] (heads interleaved); vt: bf16 [bh][32][N] (transposed).
// grid (N/64, B*H) x 256. Block = 64 Q rows, wave = 16 rows, KV tile = 64.
__global__ __launch_bounds__(256) void attn2_k(const short* __restrict__ q,
                                               const short* __restrict__ k,
                                               const short* __restrict__ vt,
                                               const float* __restrict__ pos,
                                               short* __restrict__ ob) {
  const int bh = blockIdx.y, b = bh >> 2, h = bh & 3;
  const int q0 = blockIdx.x * 64;
  __shared__ short ks_s[64 * 40];
  __shared__ short vt_s[32 * 72];
  __shared__ short ps_s[4 * 16 * 72];
  __shared__ float pqx[64], pqy[64], pkx[64], pky[64];
  const int t = threadIdx.x, w = t >> 6, lane = t & 63, g = lane >> 4, i16 = lane & 15;
  const short* kp = k + (size_t)b * NN * DIM + h * HD;
  const short* vp = vt + (size_t)bh * HD * NN;
  if (t < 64) {
    float2 pp = *(const float2*)&pos[((size_t)b * NN + q0 + t) * 2];
    pqx[t] = pp.x; pqy[t] = pp.y;
  }
  const bf16x8 qf = *(const bf16x8*)(q + (size_t)(b * NN + q0 + 16 * w + i16) * DIM + h * HD + 8 * g);
  __syncthreads();
  const float qx = pqx[16 * w + i16], qy = pqy[16 * w + i16];

  // prefetch tile 0 into registers
  bf16x8 kreg = *(const bf16x8*)(kp + (size_t)(t >> 2) * DIM + (t & 3) * 8);
  bf16x8 vreg = *(const bf16x8*)(vp + (size_t)(t >> 3) * NN + (t & 7) * 8);
  float2 kpos = make_float2(0.f, 0.f);
  if (t < 64) kpos = *(const float2*)&pos[((size_t)b * NN + t) * 2];

  f32x4 acc0 = {0.f, 0.f, 0.f, 0.f}, acc1 = {0.f, 0.f, 0.f, 0.f};
  const f32x4 zf = {0.f, 0.f, 0.f, 0.f};
  float m_run = -1e30f, l_run = 0.f;

  for (int k0 = 0; k0 < NN; k0 += 64) {
    __syncthreads();   // previous tile's readers done
    *(bf16x8*)&ks_s[(t >> 2) * 40 + (t & 3) * 8] = kreg;
    *(bf16x8*)&vt_s[(t >> 3) * 72 + (t & 7) * 8] = vreg;
    if (t < 64) { pkx[t] = kpos.x; pky[t] = kpos.y; }
    __syncthreads();
    const int kn = k0 + 64;
    if (kn < NN) {     // prefetch next tile (overlaps compute below)
      kreg = *(const bf16x8*)(kp + (size_t)(kn + (t >> 2)) * DIM + (t & 3) * 8);
      vreg = *(const bf16x8*)(vp + (size_t)(t >> 3) * NN + kn + (t & 7) * 8);
      if (t < 64) kpos = *(const float2*)&pos[((size_t)b * NN + kn + t) * 2];
    }

    // --- QK^T (swapped): sx[jt][r] = S[key 16jt+4g+r][query i16] ---
    f32x4 sx[4];
#pragma unroll
    for (int jt = 0; jt < 4; jt++) {
      bf16x8 kf = *(const bf16x8*)&ks_s[(16 * jt + i16) * 40 + 8 * g];
      sx[jt] = __builtin_amdgcn_mfma_f32_16x16x32_bf16(kf, qf, zf, 0, 0, 0);
    }

    // --- mask + online softmax (registers + 2 shuffles) ---
    float pv[16];
    float tmax = -1e30f;
#pragma unroll
    for (int jt = 0; jt < 4; jt++) {
      float4 kx4 = *(const float4*)&pkx[16 * jt + 4 * g];
      float4 ky4 = *(const float4*)&pky[16 * jt + 4 * g];
      const float kxa[4] = {kx4.x, kx4.y, kx4.z, kx4.w};
      const float kya[4] = {ky4.x, ky4.y, ky4.z, ky4.w};
#pragma unroll
      for (int r = 0; r < 4; r++) {
        const float dx = qx - kxa[r], dy = qy - kya[r];
        const float val = (dx * dx + dy * dy <= R2) ? sx[jt][r] * SCALE : -1e30f;
        pv[jt * 4 + r] = val;
        tmax = fmaxf(tmax, val);
      }
    }
    tmax = fmaxf(tmax, __shfl_xor(tmax, 16, 64));
    tmax = fmaxf(tmax, __shfl_xor(tmax, 32, 64));
    const float mnew = fmaxf(m_run, tmax);
    const float f = __expf(m_run - mnew);
    float tsum = 0.f;
    unsigned short pb[16];
#pragma unroll
    for (int u = 0; u < 16; u++) {
      const float p = __expf(pv[u] - mnew);
      tsum += p;
      pb[u] = f2bf(p);
    }
    tsum += __shfl_xor(tsum, 16, 64);
    tsum += __shfl_xor(tsum, 32, 64);
    l_run = l_run * f + tsum;
    m_run = mnew;

    // P rows -> per-wave LDS: ps[i16][16jt + 4g .. +4]
#pragma unroll
    for (int jt = 0; jt < 4; jt++) {
      bf16x4 pw;
      pw[0] = (short)pb[jt * 4 + 0]; pw[1] = (short)pb[jt * 4 + 1];
      pw[2] = (short)pb[jt * 4 + 2]; pw[3] = (short)pb[jt * 4 + 3];
      *(bf16x4*)&ps_s[w * 1152 + i16 * 72 + 16 * jt + 4 * g] = pw;
    }
    // rescale accumulators (factor for output rows 4g+r via shuffle)
    const float f0 = __shfl(f, 4 * g + 0), f1 = __shfl(f, 4 * g + 1),
                f2_ = __shfl(f, 4 * g + 2), f3 = __shfl(f, 4 * g + 3);
    acc0[0] *= f0; acc0[1] *= f1; acc0[2] *= f2_; acc0[3] *= f3;
    acc1[0] *= f0; acc1[1] *= f1; acc1[2] *= f2_; acc1[3] *= f3;

    // --- PV: O[i][d] += P[i][j] V[j][d] ---
#pragma unroll
    for (int ks2 = 0; ks2 < 2; ks2++) {
      bf16x8 pf = *(const bf16x8*)&ps_s[w * 1152 + i16 * 72 + 8 * g + 32 * ks2];
      bf16x8 vf0 = *(const bf16x8*)&vt_s[i16 * 72 + 8 * g + 32 * ks2];
      bf16x8 vf1 = *(const bf16x8*)&vt_s[(16 + i16) * 72 + 8 * g + 32 * ks2];
      acc0 = __builtin_amdgcn_mfma_f32_16x16x32_bf16(pf, vf0, acc0, 0, 0, 0);
      acc1 = __builtin_amdgcn_mfma_f32_16x16x32_bf16(pf, vf1, acc1, 0, 0, 0);
    }
  }

  // epilogue: divide by l (via shuffle), store bf16 interleaved
  const float li0 = __shfl(l_run, 4 * g + 0), li1 = __shfl(l_run, 4 * g + 1),
              li2 = __shfl(l_run, 4 * g + 2), li3 = __shfl(l_run, 4 * g + 3);
  short* op = ob + ((size_t)b * NN + q0 + 16 * w) * DIM + h * HD;
  op[(4 * g + 0) * DIM + i16] = (short)f2bf(acc0[0] / li0);
  op[(4 * g + 1) * DIM + i16] = (short)f2bf(acc0[1] / li1);
  op[(4 * g + 2) * DIM + i16] = (short)f2bf(acc0[2] / li2);
  op[(4 * g + 3) * DIM + i16] = (short)f2bf(acc0[3] / li3);
  op[(4 * g + 0) * DIM + 16 + i16] = (short)f2bf(acc1[0] / li0);
  op[(4 * g + 1) * DIM + 16 + i16] = (short)f2bf(acc1[1] / li1);
  op[(4 * g + 2) * DIM + 16 + i16] = (short)f2bf(acc1[2] / li2);
  op[(4 * g + 3) * DIM + 16 + i16] = (short)f2bf(acc1[3] / li3);
}

// ---------------------------------------------------------------------------
extern "C" void kernel_launch(void* const* d_in, const int* in_sizes, int n_in,
                              void* d_out, int out_size, void* d_ws, size_t ws_size,
                              hipStream_t stream) {
  const float* x = (const float*)d_in[0];
  const float* pos = (const float*)d_in[1];
  const float* Wq_w = (const float*)d_in[2];
  const float* Wq_b = (const float*)d_in[3];
  const float* Wk_w = (const float*)d_in[4];
  const float* Wk_b = (const float*)d_in[5];
  const float* Wv_w = (const float*)d_in[6];
  const float* Wv_b = (const float*)d_in[7];
  const float* Wo_w = (const float*)d_in[8];
  const float* Wo_b = (const float*)d_in[9];
  const float* n1_g = (const float*)d_in[10];
  const float* n1_b = (const float*)d_in[11];
  const float* n2_g = (const float*)d_in[12];
  const float* n2_b = (const float*)d_in[13];
  const float* l1_w = (const float*)d_in[14];
  const float* l1_b = (const float*)d_in[15];
  const float* l2_w = (const float*)d_in[16];
  const float* l2_b = (const float*)d_in[17];

  float* out = (float*)d_out;
  short* wsS = (short*)d_ws;
  const size_t MN = (size_t)MROWS * DIM;   // 1048576
  short* xn_bf = wsS;                      // [M][128]
  short* qb_bf = wsS + MN;                 // [M][128]
  short* kb_bf = wsS + 2 * MN;             // [M][128]
  short* vt_bf = wsS + 3 * MN;             // [bh][32][N]
  short* ob_bf = wsS + 4 * MN;             // [M][128]
  short* hb_bf = wsS + 5 * MN;             // [M][256]
  short* wT    = wsS + 7 * MN;             // 262144 shorts
  float* sums  = (float*)(wsS + 7 * MN + 262144);  // 1024 floats

  wprep_k<<<256, 256, 0, stream>>>(Wq_w, Wk_w, Wv_w, Wo_w, l1_w, l2_w, wT);
  hipMemsetAsync(sums, 0, 1024 * sizeof(float), stream);
  hipMemcpyAsync(out, x, MN * sizeof(float), hipMemcpyDeviceToDevice, stream);

  for (int l = 0; l < LYR; l++) {
    float* s1 = sums + l * 512;
    float* s2 = sums + l * 512 + 256;
    const short* lw = wT + (size_t)l * 131072;

    // --- attention block ---
    bn_stats_k<<<256, 256, 0, stream>>>(out, s1);
    bn_apply_k<<<1024, 256, 0, stream>>>(out, s1, n1_g + l * DIM, n1_b + l * DIM, xn_bf);

    gemm_bf_k<1, false><<<dim3(128, 2), 256, 0, stream>>>(
        xn_bf, lw, Wq_b + l * DIM, nullptr, nullptr, qb_bf, 128, 128);
    gemm_bf_k<1, false><<<dim3(128, 2), 256, 0, stream>>>(
        xn_bf, lw + 16384, Wk_b + l * DIM, nullptr, nullptr, kb_bf, 128, 128);
    gemm_bf_k<2, false><<<dim3(128, 2), 256, 0, stream>>>(
        xn_bf, lw + 32768, Wv_b + l * DIM, nullptr, nullptr, vt_bf, 128, 128);

    if (l == 0) rope_bf_k<<<128, 256, 0, stream>>>(qb_bf, kb_bf, pos);

    attn2_k<<<dim3(NN / 64, BB * NH), 256, 0, stream>>>(qb_bf, kb_bf, vt_bf, pos, ob_bf);

    gemm_bf_k<0, false><<<dim3(128, 2), 256, 0, stream>>>(
        ob_bf, lw + 49152, Wo_b + l * DIM, out, out, nullptr, 128, 128);

    // --- FFN block ---
    bn_stats_k<<<256, 256, 0, stream>>>(out, s2);
    bn_apply_k<<<1024, 256, 0, stream>>>(out, s2, n2_g + l * DIM, n2_b + l * DIM, xn_bf);

    gemm_bf_k<1, true><<<dim3(128, 4), 256, 0, stream>>>(
        xn_bf, lw + 65536, l1_b + l * 2 * DIM, nullptr, nullptr, hb_bf, 128, 256);
    gemm_bf_k<0, false><<<dim3(128, 2), 256, 0, stream>>>(
        hb_bf, lw + 98304, l2_b + l * DIM, out, out, nullptr, 256, 128);
  }
}

// Round 7
// 357.121 us; speedup vs baseline: 4.5836x; 1.1685x over previous
//
#include <hip/hip_runtime.h>
#include <hip/hip_bf16.h>
#include <math.h>

// Problem constants
#define LYR 2
#define DIM 128
#define NH 4
#define HD 32
#define BB 2
#define NN 4096
#define MROWS (BB * NN)          // 8192
#define R2 0.0625f               // (WINDOW/2)^2
#define BN_EPS 1e-5f
#define CLOG2E 0.25503594f       // (1/sqrt(32)) * log2(e)

typedef __attribute__((ext_vector_type(4))) float f32x4;
typedef __attribute__((ext_vector_type(8))) short bf16x8;
typedef __attribute__((ext_vector_type(4))) short bf16x4;

static __device__ inline unsigned short f2bf(float f) {
  union { float f; unsigned u; } v; v.f = f;
  unsigned r = v.u + 0x7FFFu + ((v.u >> 16) & 1u);   // round-to-nearest-even
  return (unsigned short)(r >> 16);
}

static __device__ inline float exp2_fast(float x) {
#if defined(__has_builtin)
#if __has_builtin(__builtin_amdgcn_exp2f)
  return __builtin_amdgcn_exp2f(x);
#else
  return exp2f(x);
#endif
#else
  return exp2f(x);
#endif
}

static __device__ inline unsigned cvt_pk_bf16(float lo, float hi) {
  unsigned r;
  asm volatile("v_cvt_pk_bf16_f32 %0, %1, %2" : "=v"(r) : "v"(lo), "v"(hi));
  return r;
}

// ---------------------------------------------------------------------------
// Weight prep: fp32 W[K][N] -> bf16 W^T[N][K]; Wq (and its bias) pre-scaled by
// CLOG2E so QK^T comes out in exp2 domain. Also builds qkv bias concat [2][384].
__global__ __launch_bounds__(256) void wprep_k(const float* __restrict__ Wq,
                                               const float* __restrict__ Wk,
                                               const float* __restrict__ Wv,
                                               const float* __restrict__ Wo,
                                               const float* __restrict__ L1,
                                               const float* __restrict__ L2,
                                               const float* __restrict__ Wqb,
                                               const float* __restrict__ Wkb,
                                               const float* __restrict__ Wvb,
                                               short* __restrict__ wT,
                                               float* __restrict__ qkvb) {
  const int id = blockIdx.x;
  const int l = id >> 7, r = id & 127;
  const size_t lbase = (size_t)l * 131072;
  const float* src; short* dst; int K, N, tk, tn;
  float mult = 1.0f;
  if (r < 64) {
    const int m = r >> 4, tile = r & 15;
    if (m == 0)      { src = Wq + (size_t)l * 16384; mult = CLOG2E; }
    else if (m == 1) src = Wk + (size_t)l * 16384;
    else if (m == 2) src = Wv + (size_t)l * 16384;
    else             src = Wo + (size_t)l * 16384;
    dst = wT + lbase + (size_t)m * 16384;
    K = 128; N = 128; tk = tile >> 2; tn = tile & 3;
  } else if (r < 96) {
    const int tile = r - 64;
    src = L1 + (size_t)l * 32768; dst = wT + lbase + 65536;
    K = 128; N = 256; tk = tile >> 3; tn = tile & 7;
  } else {
    const int tile = r - 96;
    src = L2 + (size_t)l * 32768; dst = wT + lbase + 98304;
    K = 256; N = 128; tk = tile >> 2; tn = tile & 3;
  }
  __shared__ float tl[32][33];
  const int t = threadIdx.x;
  const int rr = t >> 3, c4 = (t & 7) * 4;
  float4 vv = *(const float4*)(src + (size_t)(tk * 32 + rr) * N + tn * 32 + c4);
  tl[rr][c4 + 0] = vv.x; tl[rr][c4 + 1] = vv.y;
  tl[rr][c4 + 2] = vv.z; tl[rr][c4 + 3] = vv.w;
  __syncthreads();
  bf16x4 o4;
  o4[0] = (short)f2bf(tl[c4 + 0][rr] * mult);
  o4[1] = (short)f2bf(tl[c4 + 1][rr] * mult);
  o4[2] = (short)f2bf(tl[c4 + 2][rr] * mult);
  o4[3] = (short)f2bf(tl[c4 + 3][rr] * mult);
  *(bf16x4*)(dst + (size_t)(tn * 32 + rr) * K + tk * 32 + c4) = o4;
  // bias concat (one block per layer does it)
  if (r == 0) {
    for (int i = t; i < 384; i += 256) {
      float bv;
      if (i < 128)      bv = Wqb[l * 128 + i] * CLOG2E;
      else if (i < 256) bv = Wkb[l * 128 + i - 128];
      else              bv = Wvb[l * 128 + i - 256];
      qkvb[l * 384 + i] = bv;
    }
  }
}

// ---------------------------------------------------------------------------
// Copy x -> out AND accumulate BN stats (sum, sumsq per feature) into sums.
__global__ __launch_bounds__(256) void copy_stats_k(const float* __restrict__ x,
                                                    float* __restrict__ out,
                                                    float* __restrict__ sums) {
  __shared__ float ss[8][128], sq[8][128];
  const int t = threadIdx.x;
  const int c4 = (t & 31) * 4, rg = t >> 5;
  const size_t base = (size_t)blockIdx.x * (32 * DIM);
  float s0 = 0.f, s1 = 0.f, s2 = 0.f, s3 = 0.f;
  float q0 = 0.f, q1 = 0.f, q2 = 0.f, q3 = 0.f;
  for (int r = rg; r < 32; r += 8) {
    float4 v = *(const float4*)&x[base + (size_t)r * DIM + c4];
    *(float4*)&out[base + (size_t)r * DIM + c4] = v;
    s0 += v.x; q0 += v.x * v.x;
    s1 += v.y; q1 += v.y * v.y;
    s2 += v.z; q2 += v.z * v.z;
    s3 += v.w; q3 += v.w * v.w;
  }
  ss[rg][c4 + 0] = s0; sq[rg][c4 + 0] = q0;
  ss[rg][c4 + 1] = s1; sq[rg][c4 + 1] = q1;
  ss[rg][c4 + 2] = s2; sq[rg][c4 + 2] = q2;
  ss[rg][c4 + 3] = s3; sq[rg][c4 + 3] = q3;
  __syncthreads();
  if (t < 128) {
    float S = 0.f, Q = 0.f;
#pragma unroll
    for (int r2 = 0; r2 < 8; r2++) { S += ss[r2][t]; Q += sq[r2][t]; }
    atomicAdd(&sums[t], S);
    atomicAdd(&sums[128 + t], Q);
  }
}

// BN apply -> bf16. grid 1024 x 256 (4 elems/thread).
__global__ __launch_bounds__(256) void bn_apply_k(const float* __restrict__ x,
                                                  const float* __restrict__ sums,
                                                  const float* __restrict__ g,
                                                  const float* __restrict__ bta,
                                                  short* __restrict__ y) {
  const int i4 = blockIdx.x * 256 + threadIdx.x;
  const int dd = (i4 * 4) & (DIM - 1);
  const float inv = 1.0f / (float)MROWS;
  float4 xv = *(const float4*)&x[(size_t)i4 * 4];
  float4 sm = *(const float4*)&sums[dd];
  float4 sq = *(const float4*)&sums[128 + dd];
  float4 gg = *(const float4*)&g[dd];
  float4 bb = *(const float4*)&bta[dd];
  float mu0 = sm.x * inv, mu1 = sm.y * inv, mu2 = sm.z * inv, mu3 = sm.w * inv;
  bf16x4 o;
  o[0] = (short)f2bf((xv.x - mu0) * rsqrtf(sq.x * inv - mu0 * mu0 + BN_EPS) * gg.x + bb.x);
  o[1] = (short)f2bf((xv.y - mu1) * rsqrtf(sq.y * inv - mu1 * mu1 + BN_EPS) * gg.y + bb.y);
  o[2] = (short)f2bf((xv.z - mu2) * rsqrtf(sq.z * inv - mu2 * mu2 + BN_EPS) * gg.z + bb.z);
  o[3] = (short)f2bf((xv.w - mu3) * rsqrtf(sq.w * inv - mu3 * mu3 + BN_EPS) * gg.w + bb.w);
  *(bf16x4*)&y[(size_t)i4 * 4] = o;
}

// ---------------------------------------------------------------------------
// bf16 MFMA GEMM. A bf16 [M][K], WT bf16 [Nn][K]. BM=BN=64, BK=64, 256 thr.
// MODE 0: fp32 out = acc + bias + res, AND fused BN-stats into statsums.
// MODE 1: bf16 row-major out (optional RELU)
// MODE 3: fused QKV split: cols 0-127 -> Cb (q), 128-255 -> Cb+MN (k),
//         256-383 -> transposed head-major v at Cb+2*MN.
template <int MODE, bool RELU>
__global__ __launch_bounds__(256) void gemm_bf_k(const short* __restrict__ A,
                                                 const short* __restrict__ WT,
                                                 const float* __restrict__ bias,
                                                 const float* res,
                                                 float* Cf,
                                                 short* __restrict__ Cb,
                                                 float* __restrict__ statsums,
                                                 int K) {
  __shared__ short a_s[64 * 80];
  __shared__ short w_s[64 * 80];
  const int t = threadIdx.x, w = t >> 6, lane = t & 63, g = lane >> 4, i16 = lane & 15;
  const int bm = blockIdx.x * 64, bn = blockIdx.y * 64;
  const int sr = t >> 2, sc = (t & 3) * 8;
  const size_t MN = (size_t)MROWS * DIM;
  f32x4 acc[4];
#pragma unroll
  for (int ct = 0; ct < 4; ct++) acc[ct] = (f32x4){0.f, 0.f, 0.f, 0.f};
  for (int k0 = 0; k0 < K; k0 += 64) {
    __syncthreads();
    *(bf16x8*)&a_s[sr * 80 + sc]      = *(const bf16x8*)(A + (size_t)(bm + sr) * K + k0 + sc);
    *(bf16x8*)&a_s[sr * 80 + sc + 32] = *(const bf16x8*)(A + (size_t)(bm + sr) * K + k0 + sc + 32);
    *(bf16x8*)&w_s[sr * 80 + sc]      = *(const bf16x8*)(WT + (size_t)(bn + sr) * K + k0 + sc);
    *(bf16x8*)&w_s[sr * 80 + sc + 32] = *(const bf16x8*)(WT + (size_t)(bn + sr) * K + k0 + sc + 32);
    __syncthreads();
#pragma unroll
    for (int ks = 0; ks < 2; ks++) {
      bf16x8 af = *(const bf16x8*)&a_s[(16 * w + i16) * 80 + ks * 32 + 8 * g];
#pragma unroll
      for (int ct = 0; ct < 4; ct++) {
        bf16x8 wf = *(const bf16x8*)&w_s[(ct * 16 + i16) * 80 + ks * 32 + 8 * g];
        acc[ct] = __builtin_amdgcn_mfma_f32_16x16x32_bf16(af, wf, acc[ct], 0, 0, 0);
      }
    }
  }
  float s_acc[4], q_acc[4];
#pragma unroll
  for (int ct = 0; ct < 4; ct++) {
    const int col = bn + ct * 16 + i16;
    const float bv = bias[col];
    if (MODE == 3) {
      const int row0 = bm + 16 * w + 4 * g;
      if (col < 256) {
        short* dstb = (col < 128) ? Cb : (Cb + MN);
        const int cc = col & 127;
#pragma unroll
        for (int r = 0; r < 4; r++)
          dstb[(size_t)(row0 + r) * DIM + cc] = (short)f2bf(acc[ct][r] + bv);
      } else {
        const int b_ = row0 >> 12, n_ = row0 & (NN - 1);
        const int hh = (col - 256) >> 5, dd = (col - 256) & 31;
        bf16x4 o4;
#pragma unroll
        for (int r = 0; r < 4; r++) o4[r] = (short)f2bf(acc[ct][r] + bv);
        *(bf16x4*)(Cb + 2 * MN + ((size_t)(b_ * NH + hh) * HD + dd) * NN + n_) = o4;
      }
    } else if (MODE == 0) {
      float ssum = 0.f, qsum = 0.f;
#pragma unroll
      for (int r = 0; r < 4; r++) {
        const int row = bm + 16 * w + 4 * g + r;
        float vv = acc[ct][r] + bv + res[(size_t)row * DIM + col];
        Cf[(size_t)row * DIM + col] = vv;
        ssum += vv; qsum += vv * vv;
      }
      s_acc[ct] = ssum; q_acc[ct] = qsum;
    } else {
#pragma unroll
      for (int r = 0; r < 4; r++) {
        const int row = bm + 16 * w + 4 * g + r;
        float vv = acc[ct][r] + bv;
        if (RELU) vv = fmaxf(vv, 0.f);
        Cb[(size_t)row * (size_t)256 + col] = (short)f2bf(vv);  // MODE1 only used with Nn=256
      }
    }
  }
  if (MODE == 0) {
    // reduce stats: over g (shfl), over waves (LDS atomics), then global atomics
#pragma unroll
    for (int ct = 0; ct < 4; ct++) {
      s_acc[ct] += __shfl_xor(s_acc[ct], 16, 64);
      s_acc[ct] += __shfl_xor(s_acc[ct], 32, 64);
      q_acc[ct] += __shfl_xor(q_acc[ct], 16, 64);
      q_acc[ct] += __shfl_xor(q_acc[ct], 32, 64);
    }
    float* bs = (float*)a_s;
    __syncthreads();
    if (t < 128) bs[t] = 0.f;
    __syncthreads();
    if (lane < 16) {
#pragma unroll
      for (int ct = 0; ct < 4; ct++) {
        atomicAdd(&bs[ct * 16 + i16], s_acc[ct]);
        atomicAdd(&bs[64 + ct * 16 + i16], q_acc[ct]);
      }
    }
    __syncthreads();
    if (t < 64) {
      atomicAdd(&statsums[bn + t], bs[t]);
      atomicAdd(&statsums[128 + bn + t], bs[64 + t]);
    }
  }
}

// ---------------------------------------------------------------------------
// RoPE in place on bf16 q,k (layer 0). q is pre-scaled; rotation commutes.
__global__ __launch_bounds__(256) void rope_bf_k(short* __restrict__ q,
                                                 short* __restrict__ kk,
                                                 const float* __restrict__ pos) {
  const int idx = blockIdx.x * 256 + threadIdx.x;   // 32768
  const int row = idx >> 2, hh = idx & 3;
  const float2 pp = *(const float2*)&pos[(size_t)row * 2];
  short* qp = q + (size_t)row * DIM + hh * HD;
  short* kp = kk + (size_t)row * DIM + hh * HD;
  bf16x8 qv[4], kv[4];
#pragma unroll
  for (int u = 0; u < 4; u++) {
    qv[u] = *(const bf16x8*)(qp + 8 * u);
    kv[u] = *(const bf16x8*)(kp + 8 * u);
  }
#pragma unroll
  for (int lp = 0; lp < 16; lp++) {
    const int p = hh * 16 + lp;
    const float coord = (p < 32) ? pp.x : pp.y;
    const int f = p & 31;
    float sn, cs;
    __sincosf(3.14159265358979323846f * (float)(f + 1) * coord, &sn, &cs);
    const int u = lp >> 2, e = (lp & 3) * 2;
    const float a0 = __uint_as_float(((unsigned)(unsigned short)qv[u][e]) << 16);
    const float a1 = __uint_as_float(((unsigned)(unsigned short)qv[u][e + 1]) << 16);
    qv[u][e]     = (short)f2bf(cs * a0 - sn * a1);
    qv[u][e + 1] = (short)f2bf(cs * a1 + sn * a0);
    const float b0 = __uint_as_float(((unsigned)(unsigned short)kv[u][e]) << 16);
    const float b1 = __uint_as_float(((unsigned)(unsigned short)kv[u][e + 1]) << 16);
    kv[u][e]     = (short)f2bf(cs * b0 - sn * b1);
    kv[u][e + 1] = (short)f2bf(cs * b1 + sn * b0);
  }
#pragma unroll
  for (int u = 0; u < 4; u++) {
    *(bf16x8*)(qp + 8 * u) = qv[u];
    *(bf16x8*)(kp + 8 * u) = kv[u];
  }
}

// ---------------------------------------------------------------------------
// MFMA flash attention. Q pre-scaled by CLOG2E -> scores in exp2 domain.
// grid (N/32, B*H) x 128 threads (2 waves). Wave = 16 Q rows. KV tile = 64.
// Mask: dot(pq,pk) >= c_i - |pk|^2/2 form (2 fma + cmp + sel per score).
__global__ __launch_bounds__(128) void attn3_k(const short* __restrict__ q,
                                               const short* __restrict__ k,
                                               const short* __restrict__ vt,
                                               const float* __restrict__ pos,
                                               short* __restrict__ ob) {
  const int bh = blockIdx.y, b = bh >> 2, h = bh & 3;
  const int q0 = blockIdx.x * 32;
  __shared__ short ks_s[64 * 40];
  __shared__ short vt_s[32 * 72];
  __shared__ short ps_s[2 * 16 * 72];
  __shared__ float pkx[64], pky[64], pnt[64];
  const int t = threadIdx.x, w = t >> 6, lane = t & 63, g = lane >> 4, i16 = lane & 15;
  const short* kp = k + (size_t)b * NN * DIM + h * HD;
  const short* vp = vt + (size_t)bh * HD * NN;

  const bf16x8 qf = *(const bf16x8*)(q + (size_t)(b * NN + q0 + 16 * w + i16) * DIM + h * HD + 8 * g);
  const float2 qp2 = *(const float2*)&pos[((size_t)b * NN + q0 + 16 * w + i16) * 2];
  const float qx = qp2.x, qy = qp2.y;
  const float ci = 0.5f * (qx * qx + qy * qy) - 0.5f * R2;

  // prefetch tile 0
  bf16x8 kreg0 = *(const bf16x8*)(kp + (size_t)(t >> 2) * DIM + (t & 3) * 8);
  bf16x8 kreg1 = *(const bf16x8*)(kp + (size_t)((t >> 2) + 32) * DIM + (t & 3) * 8);
  bf16x8 vreg0 = *(const bf16x8*)(vp + (size_t)(t >> 3) * NN + (t & 7) * 8);
  bf16x8 vreg1 = *(const bf16x8*)(vp + (size_t)((t >> 3) + 16) * NN + (t & 7) * 8);
  float2 kpos = make_float2(0.f, 0.f);
  if (t < 64) kpos = *(const float2*)&pos[((size_t)b * NN + t) * 2];

  f32x4 acc0 = {0.f, 0.f, 0.f, 0.f}, acc1 = {0.f, 0.f, 0.f, 0.f};
  const f32x4 zf = {0.f, 0.f, 0.f, 0.f};
  float m_run = -1e30f, l_run = 0.f;

  for (int k0 = 0; k0 < NN; k0 += 64) {
    __syncthreads();
    *(bf16x8*)&ks_s[(t >> 2) * 40 + (t & 3) * 8] = kreg0;
    *(bf16x8*)&ks_s[((t >> 2) + 32) * 40 + (t & 3) * 8] = kreg1;
    *(bf16x8*)&vt_s[(t >> 3) * 72 + (t & 7) * 8] = vreg0;
    *(bf16x8*)&vt_s[((t >> 3) + 16) * 72 + (t & 7) * 8] = vreg1;
    if (t < 64) {
      pkx[t] = kpos.x; pky[t] = kpos.y;
      pnt[t] = -0.5f * (kpos.x * kpos.x + kpos.y * kpos.y);
    }
    __syncthreads();
    const int kn = k0 + 64;
    if (kn < NN) {
      kreg0 = *(const bf16x8*)(kp + (size_t)(kn + (t >> 2)) * DIM + (t & 3) * 8);
      kreg1 = *(const bf16x8*)(kp + (size_t)(kn + 32 + (t >> 2)) * DIM + (t & 3) * 8);
      vreg0 = *(const bf16x8*)(vp + (size_t)(t >> 3) * NN + kn + (t & 7) * 8);
      vreg1 = *(const bf16x8*)(vp + (size_t)((t >> 3) + 16) * NN + kn + (t & 7) * 8);
      if (t < 64) kpos = *(const float2*)&pos[((size_t)b * NN + kn + t) * 2];
    }

    // --- QK^T (swapped): sx[jt][r] = S2[key 16jt+4g+r][query i16] (exp2 dom)
    f32x4 sx[4];
#pragma unroll
    for (int jt = 0; jt < 4; jt++) {
      bf16x8 kf = *(const bf16x8*)&ks_s[(16 * jt + i16) * 40 + 8 * g];
      sx[jt] = __builtin_amdgcn_mfma_f32_16x16x32_bf16(kf, qf, zf, 0, 0, 0);
    }

    // --- mask (dot-threshold) + online softmax, exp2 domain ---
    float pv_[16];
    float tmax = -1e30f;
#pragma unroll
    for (int jt = 0; jt < 4; jt++) {
      float4 kx4 = *(const float4*)&pkx[16 * jt + 4 * g];
      float4 ky4 = *(const float4*)&pky[16 * jt + 4 * g];
      float4 nt4 = *(const float4*)&pnt[16 * jt + 4 * g];
      const float kxa[4] = {kx4.x, kx4.y, kx4.z, kx4.w};
      const float kya[4] = {ky4.x, ky4.y, ky4.z, ky4.w};
      const float nta[4] = {nt4.x, nt4.y, nt4.z, nt4.w};
#pragma unroll
      for (int r = 0; r < 4; r++) {
        const float dot = fmaf(qx, kxa[r], fmaf(qy, kya[r], nta[r]));
        const float val = (dot >= ci) ? sx[jt][r] : -1e30f;
        pv_[jt * 4 + r] = val;
        tmax = fmaxf(tmax, val);
      }
    }
    tmax = fmaxf(tmax, __shfl_xor(tmax, 16, 64));
    tmax = fmaxf(tmax, __shfl_xor(tmax, 32, 64));
    const float mnew = fmaxf(m_run, tmax);
    const float f = exp2_fast(m_run - mnew);
    float tsum = 0.f;
    float pr[16];
#pragma unroll
    for (int u = 0; u < 16; u++) {
      pr[u] = exp2_fast(pv_[u] - mnew);
      tsum += pr[u];
    }
    tsum += __shfl_xor(tsum, 16, 64);
    tsum += __shfl_xor(tsum, 32, 64);
    l_run = l_run * f + tsum;
    m_run = mnew;

    // P rows -> per-wave LDS (packed bf16 via v_cvt_pk_bf16_f32)
#pragma unroll
    for (int jt = 0; jt < 4; jt++) {
      uint2 w2;
      w2.x = cvt_pk_bf16(pr[jt * 4 + 0], pr[jt * 4 + 1]);
      w2.y = cvt_pk_bf16(pr[jt * 4 + 2], pr[jt * 4 + 3]);
      *(uint2*)&ps_s[w * 1152 + i16 * 72 + 16 * jt + 4 * g] = w2;
    }
    // rescale accumulators
    const float f0 = __shfl(f, 4 * g + 0), f1 = __shfl(f, 4 * g + 1),
                f2_ = __shfl(f, 4 * g + 2), f3 = __shfl(f, 4 * g + 3);
    acc0[0] *= f0; acc0[1] *= f1; acc0[2] *= f2_; acc0[3] *= f3;
    acc1[0] *= f0; acc1[1] *= f1; acc1[2] *= f2_; acc1[3] *= f3;

    // --- PV ---
#pragma unroll
    for (int ks2 = 0; ks2 < 2; ks2++) {
      bf16x8 pf = *(const bf16x8*)&ps_s[w * 1152 + i16 * 72 + 8 * g + 32 * ks2];
      bf16x8 vf0 = *(const bf16x8*)&vt_s[i16 * 72 + 8 * g + 32 * ks2];
      bf16x8 vf1 = *(const bf16x8*)&vt_s[(16 + i16) * 72 + 8 * g + 32 * ks2];
      acc0 = __builtin_amdgcn_mfma_f32_16x16x32_bf16(pf, vf0, acc0, 0, 0, 0);
      acc1 = __builtin_amdgcn_mfma_f32_16x16x32_bf16(pf, vf1, acc1, 0, 0, 0);
    }
  }

  // epilogue
  const float li0 = __shfl(l_run, 4 * g + 0), li1 = __shfl(l_run, 4 * g + 1),
              li2 = __shfl(l_run, 4 * g + 2), li3 = __shfl(l_run, 4 * g + 3);
  short* op = ob + ((size_t)b * NN + q0 + 16 * w) * DIM + h * HD;
  op[(4 * g + 0) * DIM + i16] = (short)f2bf(acc0[0] / li0);
  op[(4 * g + 1) * DIM + i16] = (short)f2bf(acc0[1] / li1);
  op[(4 * g + 2) * DIM + i16] = (short)f2bf(acc0[2] / li2);
  op[(4 * g + 3) * DIM + i16] = (short)f2bf(acc0[3] / li3);
  op[(4 * g + 0) * DIM + 16 + i16] = (short)f2bf(acc1[0] / li0);
  op[(4 * g + 1) * DIM + 16 + i16] = (short)f2bf(acc1[1] / li1);
  op[(4 * g + 2) * DIM + 16 + i16] = (short)f2bf(acc1[2] / li2);
  op[(4 * g + 3) * DIM + 16 + i16] = (short)f2bf(acc1[3] / li3);
}

// ---------------------------------------------------------------------------
extern "C" void kernel_launch(void* const* d_in, const int* in_sizes, int n_in,
                              void* d_out, int out_size, void* d_ws, size_t ws_size,
                              hipStream_t stream) {
  const float* x = (const float*)d_in[0];
  const float* pos = (const float*)d_in[1];
  const float* Wq_w = (const float*)d_in[2];
  const float* Wq_b = (const float*)d_in[3];
  const float* Wk_w = (const float*)d_in[4];
  const float* Wk_b = (const float*)d_in[5];
  const float* Wv_w = (const float*)d_in[6];
  const float* Wv_b = (const float*)d_in[7];
  const float* Wo_w = (const float*)d_in[8];
  const float* Wo_b = (const float*)d_in[9];
  const float* n1_g = (const float*)d_in[10];
  const float* n1_b = (const float*)d_in[11];
  const float* n2_g = (const float*)d_in[12];
  const float* n2_b = (const float*)d_in[13];
  const float* l1_w = (const float*)d_in[14];
  const float* l1_b = (const float*)d_in[15];
  const float* l2_w = (const float*)d_in[16];
  const float* l2_b = (const float*)d_in[17];

  float* out = (float*)d_out;
  short* wsS = (short*)d_ws;
  const size_t MN = (size_t)MROWS * DIM;   // 1048576
  short* xn_bf = wsS;                      // [M][128]
  short* qb_bf = wsS + MN;                 // [M][128]  (followed by kb, vt)
  short* ob_bf = wsS + 4 * MN;             // [M][128]
  short* hb_bf = wsS + 5 * MN;             // [M][256]
  short* wT    = wsS + 7 * MN;             // 262144 shorts
  float* qkvb  = (float*)(wsS + 7 * MN + 262144);  // 768 floats
  float* sums  = qkvb + 768;               // 5 slots x 256 floats

  wprep_k<<<256, 256, 0, stream>>>(Wq_w, Wk_w, Wv_w, Wo_w, l1_w, l2_w,
                                   Wq_b, Wk_b, Wv_b, wT, qkvb);
  hipMemsetAsync(sums, 0, 1280 * sizeof(float), stream);
  copy_stats_k<<<256, 256, 0, stream>>>(x, out, sums);   // slot 0 = n1, l0

  for (int l = 0; l < LYR; l++) {
    const short* lw = wT + (size_t)l * 131072;
    float* s_n1 = sums + (2 * l) * 256;
    float* s_n2 = sums + (2 * l + 1) * 256;
    float* s_nx = sums + (2 * l + 2) * 256;   // next layer's n1 (or dummy)

    // --- attention block ---
    bn_apply_k<<<1024, 256, 0, stream>>>(out, s_n1, n1_g + l * DIM, n1_b + l * DIM, xn_bf);
    gemm_bf_k<3, false><<<dim3(128, 6), 256, 0, stream>>>(
        xn_bf, lw, qkvb + l * 384, nullptr, nullptr, qb_bf, nullptr, 128);
    if (l == 0) rope_bf_k<<<128, 256, 0, stream>>>(qb_bf, qb_bf + MN, pos);
    attn3_k<<<dim3(NN / 32, BB * NH), 128, 0, stream>>>(
        qb_bf, qb_bf + MN, qb_bf + 2 * MN, pos, ob_bf);
    gemm_bf_k<0, false><<<dim3(128, 2), 256, 0, stream>>>(
        ob_bf, lw + 49152, Wo_b + l * DIM, out, out, nullptr, s_n2, 128);

    // --- FFN block ---
    bn_apply_k<<<1024, 256, 0, stream>>>(out, s_n2, n2_g + l * DIM, n2_b + l * DIM, xn_bf);
    gemm_bf_k<1, true><<<dim3(128, 4), 256, 0, stream>>>(
        xn_bf, lw + 65536, l1_b + l * 2 * DIM, nullptr, nullptr, hb_bf, nullptr, 128);
    gemm_bf_k<0, false><<<dim3(128, 2), 256, 0, stream>>>(
        hb_bf, lw + 98304, l2_b + l * DIM, out, out, nullptr, s_nx, 256);
  }
}

// Round 10
// 308.077 us; speedup vs baseline: 5.3133x; 1.1592x over previous
//
#include <hip/hip_runtime.h>
#include <hip/hip_bf16.h>
#include <math.h>

// Problem constants
#define LYR 2
#define DIM 128
#define NH 4
#define HD 32
#define BB 2
#define NN 4096
#define MROWS (BB * NN)          // 8192
#define R2 0.0625f               // (WINDOW/2)^2
#define BN_EPS 1e-5f
#define CLOG2E 0.25503594f       // (1/sqrt(32)) * log2(e)
#define NCH 4                    // KV-split chunks
#define CHLEN (NN / NCH)         // 1024 keys per chunk

typedef __attribute__((ext_vector_type(4))) float f32x4;
typedef __attribute__((ext_vector_type(8))) short bf16x8;
typedef __attribute__((ext_vector_type(4))) short bf16x4;

static __device__ inline unsigned short f2bf(float f) {
  union { float f; unsigned u; } v; v.f = f;
  unsigned r = v.u + 0x7FFFu + ((v.u >> 16) & 1u);   // round-to-nearest-even
  return (unsigned short)(r >> 16);
}

static __device__ inline float exp2_fast(float x) {
#if defined(__has_builtin)
#if __has_builtin(__builtin_amdgcn_exp2f)
  return __builtin_amdgcn_exp2f(x);
#else
  return exp2f(x);
#endif
#else
  return exp2f(x);
#endif
}

static __device__ inline unsigned cvt_pk_bf16(float lo, float hi) {
  unsigned r;
  asm volatile("v_cvt_pk_bf16_f32 %0, %1, %2" : "=v"(r) : "v"(lo), "v"(hi));
  return r;
}

// ---------------------------------------------------------------------------
// Weight prep: fp32 W[K][N] -> bf16 W^T[N][K]; Wq (and its bias) pre-scaled by
// CLOG2E so QK^T comes out in exp2 domain. Also builds qkv bias concat [2][384].
__global__ __launch_bounds__(256) void wprep_k(const float* __restrict__ Wq,
                                               const float* __restrict__ Wk,
                                               const float* __restrict__ Wv,
                                               const float* __restrict__ Wo,
                                               const float* __restrict__ L1,
                                               const float* __restrict__ L2,
                                               const float* __restrict__ Wqb,
                                               const float* __restrict__ Wkb,
                                               const float* __restrict__ Wvb,
                                               short* __restrict__ wT,
                                               float* __restrict__ qkvb) {
  const int id = blockIdx.x;
  const int l = id >> 7, r = id & 127;
  const size_t lbase = (size_t)l * 131072;
  const float* src; short* dst; int K, N, tk, tn;
  float mult = 1.0f;
  if (r < 64) {
    const int m = r >> 4, tile = r & 15;
    if (m == 0)      { src = Wq + (size_t)l * 16384; mult = CLOG2E; }
    else if (m == 1) src = Wk + (size_t)l * 16384;
    else if (m == 2) src = Wv + (size_t)l * 16384;
    else             src = Wo + (size_t)l * 16384;
    dst = wT + lbase + (size_t)m * 16384;
    K = 128; N = 128; tk = tile >> 2; tn = tile & 3;
  } else if (r < 96) {
    const int tile = r - 64;
    src = L1 + (size_t)l * 32768; dst = wT + lbase + 65536;
    K = 128; N = 256; tk = tile >> 3; tn = tile & 7;
  } else {
    const int tile = r - 96;
    src = L2 + (size_t)l * 32768; dst = wT + lbase + 98304;
    K = 256; N = 128; tk = tile >> 2; tn = tile & 3;
  }
  __shared__ float tl[32][33];
  const int t = threadIdx.x;
  const int rr = t >> 3, c4 = (t & 7) * 4;
  float4 vv = *(const float4*)(src + (size_t)(tk * 32 + rr) * N + tn * 32 + c4);
  tl[rr][c4 + 0] = vv.x; tl[rr][c4 + 1] = vv.y;
  tl[rr][c4 + 2] = vv.z; tl[rr][c4 + 3] = vv.w;
  __syncthreads();
  bf16x4 o4;
  o4[0] = (short)f2bf(tl[c4 + 0][rr] * mult);
  o4[1] = (short)f2bf(tl[c4 + 1][rr] * mult);
  o4[2] = (short)f2bf(tl[c4 + 2][rr] * mult);
  o4[3] = (short)f2bf(tl[c4 + 3][rr] * mult);
  *(bf16x4*)(dst + (size_t)(tn * 32 + rr) * K + tk * 32 + c4) = o4;
  // bias concat (one block per layer does it)
  if (r == 0) {
    for (int i = t; i < 384; i += 256) {
      float bv;
      if (i < 128)      bv = Wqb[l * 128 + i] * CLOG2E;
      else if (i < 256) bv = Wkb[l * 128 + i - 128];
      else              bv = Wvb[l * 128 + i - 256];
      qkvb[l * 384 + i] = bv;
    }
  }
}

// ---------------------------------------------------------------------------
// Copy x -> out AND accumulate BN stats (sum, sumsq per feature) into sums.
__global__ __launch_bounds__(256) void copy_stats_k(const float* __restrict__ x,
                                                    float* __restrict__ out,
                                                    float* __restrict__ sums) {
  __shared__ float ss[8][128], sq[8][128];
  const int t = threadIdx.x;
  const int c4 = (t & 31) * 4, rg = t >> 5;
  const size_t base = (size_t)blockIdx.x * (32 * DIM);
  float s0 = 0.f, s1 = 0.f, s2 = 0.f, s3 = 0.f;
  float q0 = 0.f, q1 = 0.f, q2 = 0.f, q3 = 0.f;
  for (int r = rg; r < 32; r += 8) {
    float4 v = *(const float4*)&x[base + (size_t)r * DIM + c4];
    *(float4*)&out[base + (size_t)r * DIM + c4] = v;
    s0 += v.x; q0 += v.x * v.x;
    s1 += v.y; q1 += v.y * v.y;
    s2 += v.z; q2 += v.z * v.z;
    s3 += v.w; q3 += v.w * v.w;
  }
  ss[rg][c4 + 0] = s0; sq[rg][c4 + 0] = q0;
  ss[rg][c4 + 1] = s1; sq[rg][c4 + 1] = q1;
  ss[rg][c4 + 2] = s2; sq[rg][c4 + 2] = q2;
  ss[rg][c4 + 3] = s3; sq[rg][c4 + 3] = q3;
  __syncthreads();
  if (t < 128) {
    float S = 0.f, Q = 0.f;
#pragma unroll
    for (int r2 = 0; r2 < 8; r2++) { S += ss[r2][t]; Q += sq[r2][t]; }
    atomicAdd(&sums[t], S);
    atomicAdd(&sums[128 + t], Q);
  }
}

// ---------------------------------------------------------------------------
// bf16 MFMA GEMM. WT bf16 [Nn][K]. BM=BN=64, BK=64, 256 thr.
// ABN=true: A is fp32 Af[M][K] normalized on the fly with BatchNorm stats
//           (scale/shift precomputed into LDS) then converted to bf16.
// ABN=false: A is bf16 [M][K].
// MODE 0: fp32 out = acc + bias + res, AND fused BN-stats into statsums.
// MODE 1: bf16 row-major out stride 256 (optional RELU) -- FFN1 only.
// MODE 3: fused QKV split: cols 0-127 -> Cb (q), 128-255 -> Cb+MN (k),
//         256-383 -> transposed head-major v at Cb+2*MN.
template <int MODE, bool RELU, bool ABN>
__global__ __launch_bounds__(256) void gemm_bf_k(const short* __restrict__ A,
                                                 const float* __restrict__ Af,
                                                 const float* __restrict__ stats,
                                                 const float* __restrict__ gma,
                                                 const float* __restrict__ btaN,
                                                 const short* __restrict__ WT,
                                                 const float* __restrict__ bias,
                                                 const float* res,
                                                 float* Cf,
                                                 short* __restrict__ Cb,
                                                 float* __restrict__ statsums,
                                                 int K) {
  __shared__ short a_s[64 * 80];
  __shared__ short w_s[64 * 80];
  __shared__ float sc_s[128], sh_s[128];
  const int t = threadIdx.x, w = t >> 6, lane = t & 63, g = lane >> 4, i16 = lane & 15;
  const int bm = blockIdx.x * 64, bn = blockIdx.y * 64;
  const int sr = t >> 2, sc = (t & 3) * 8, c16 = (t & 3) * 16;
  const size_t MN = (size_t)MROWS * DIM;
  if (ABN) {
    if (t < 128) {
      const float inv = 1.0f / (float)MROWS;
      const float mu = stats[t] * inv;
      const float var = stats[128 + t] * inv - mu * mu;
      const float rs = rsqrtf(var + BN_EPS);
      const float s = rs * gma[t];
      sc_s[t] = s;
      sh_s[t] = btaN[t] - mu * s;
    }
  }
  f32x4 acc[4];
#pragma unroll
  for (int ct = 0; ct < 4; ct++) acc[ct] = (f32x4){0.f, 0.f, 0.f, 0.f};
  for (int k0 = 0; k0 < K; k0 += 64) {
    __syncthreads();
    if (ABN) {
      const float* ap = Af + (size_t)(bm + sr) * K + k0 + c16;
      float4 x0 = *(const float4*)ap, x1 = *(const float4*)(ap + 4);
      float4 x2 = *(const float4*)(ap + 8), x3 = *(const float4*)(ap + 12);
      const int kb = k0 + c16;
      bf16x8 o0, o1;
      o0[0] = (short)f2bf(x0.x * sc_s[kb + 0]  + sh_s[kb + 0]);
      o0[1] = (short)f2bf(x0.y * sc_s[kb + 1]  + sh_s[kb + 1]);
      o0[2] = (short)f2bf(x0.z * sc_s[kb + 2]  + sh_s[kb + 2]);
      o0[3] = (short)f2bf(x0.w * sc_s[kb + 3]  + sh_s[kb + 3]);
      o0[4] = (short)f2bf(x1.x * sc_s[kb + 4]  + sh_s[kb + 4]);
      o0[5] = (short)f2bf(x1.y * sc_s[kb + 5]  + sh_s[kb + 5]);
      o0[6] = (short)f2bf(x1.z * sc_s[kb + 6]  + sh_s[kb + 6]);
      o0[7] = (short)f2bf(x1.w * sc_s[kb + 7]  + sh_s[kb + 7]);
      o1[0] = (short)f2bf(x2.x * sc_s[kb + 8]  + sh_s[kb + 8]);
      o1[1] = (short)f2bf(x2.y * sc_s[kb + 9]  + sh_s[kb + 9]);
      o1[2] = (short)f2bf(x2.z * sc_s[kb + 10] + sh_s[kb + 10]);
      o1[3] = (short)f2bf(x2.w * sc_s[kb + 11] + sh_s[kb + 11]);
      o1[4] = (short)f2bf(x3.x * sc_s[kb + 12] + sh_s[kb + 12]);
      o1[5] = (short)f2bf(x3.y * sc_s[kb + 13] + sh_s[kb + 13]);
      o1[6] = (short)f2bf(x3.z * sc_s[kb + 14] + sh_s[kb + 14]);
      o1[7] = (short)f2bf(x3.w * sc_s[kb + 15] + sh_s[kb + 15]);
      *(bf16x8*)&a_s[sr * 80 + c16] = o0;
      *(bf16x8*)&a_s[sr * 80 + c16 + 8] = o1;
    } else {
      *(bf16x8*)&a_s[sr * 80 + sc]      = *(const bf16x8*)(A + (size_t)(bm + sr) * K + k0 + sc);
      *(bf16x8*)&a_s[sr * 80 + sc + 32] = *(const bf16x8*)(A + (size_t)(bm + sr) * K + k0 + sc + 32);
    }
    *(bf16x8*)&w_s[sr * 80 + sc]      = *(const bf16x8*)(WT + (size_t)(bn + sr) * K + k0 + sc);
    *(bf16x8*)&w_s[sr * 80 + sc + 32] = *(const bf16x8*)(WT + (size_t)(bn + sr) * K + k0 + sc + 32);
    __syncthreads();
#pragma unroll
    for (int ks = 0; ks < 2; ks++) {
      bf16x8 af = *(const bf16x8*)&a_s[(16 * w + i16) * 80 + ks * 32 + 8 * g];
#pragma unroll
      for (int ct = 0; ct < 4; ct++) {
        bf16x8 wf = *(const bf16x8*)&w_s[(ct * 16 + i16) * 80 + ks * 32 + 8 * g];
        acc[ct] = __builtin_amdgcn_mfma_f32_16x16x32_bf16(af, wf, acc[ct], 0, 0, 0);
      }
    }
  }
  float s_acc[4], q_acc[4];
#pragma unroll
  for (int ct = 0; ct < 4; ct++) {
    const int col = bn + ct * 16 + i16;
    const float bv = bias[col];
    if (MODE == 3) {
      const int row0 = bm + 16 * w + 4 * g;
      if (col < 256) {
        short* dstb = (col < 128) ? Cb : (Cb + MN);
        const int cc = col & 127;
#pragma unroll
        for (int r = 0; r < 4; r++)
          dstb[(size_t)(row0 + r) * DIM + cc] = (short)f2bf(acc[ct][r] + bv);
      } else {
        const int b_ = row0 >> 12, n_ = row0 & (NN - 1);
        const int hh = (col - 256) >> 5, dd = (col - 256) & 31;
        bf16x4 o4;
#pragma unroll
        for (int r = 0; r < 4; r++) o4[r] = (short)f2bf(acc[ct][r] + bv);
        *(bf16x4*)(Cb + 2 * MN + ((size_t)(b_ * NH + hh) * HD + dd) * NN + n_) = o4;
      }
    } else if (MODE == 0) {
      float ssum = 0.f, qsum = 0.f;
#pragma unroll
      for (int r = 0; r < 4; r++) {
        const int row = bm + 16 * w + 4 * g + r;
        float vv = acc[ct][r] + bv + res[(size_t)row * DIM + col];
        Cf[(size_t)row * DIM + col] = vv;
        ssum += vv; qsum += vv * vv;
      }
      s_acc[ct] = ssum; q_acc[ct] = qsum;
    } else {
#pragma unroll
      for (int r = 0; r < 4; r++) {
        const int row = bm + 16 * w + 4 * g + r;
        float vv = acc[ct][r] + bv;
        if (RELU) vv = fmaxf(vv, 0.f);
        Cb[(size_t)row * (size_t)256 + col] = (short)f2bf(vv);  // MODE1 only (Nn=256)
      }
    }
  }
  if (MODE == 0) {
#pragma unroll
    for (int ct = 0; ct < 4; ct++) {
      s_acc[ct] += __shfl_xor(s_acc[ct], 16, 64);
      s_acc[ct] += __shfl_xor(s_acc[ct], 32, 64);
      q_acc[ct] += __shfl_xor(q_acc[ct], 16, 64);
      q_acc[ct] += __shfl_xor(q_acc[ct], 32, 64);
    }
    float* bs = (float*)a_s;
    __syncthreads();
    if (t < 128) bs[t] = 0.f;
    __syncthreads();
    if (lane < 16) {
#pragma unroll
      for (int ct = 0; ct < 4; ct++) {
        atomicAdd(&bs[ct * 16 + i16], s_acc[ct]);
        atomicAdd(&bs[64 + ct * 16 + i16], q_acc[ct]);
      }
    }
    __syncthreads();
    if (t < 64) {
      atomicAdd(&statsums[bn + t], bs[t]);
      atomicAdd(&statsums[128 + bn + t], bs[64 + t]);
    }
  }
}

// ---------------------------------------------------------------------------
// RoPE in place on bf16 q,k (layer 0). q is pre-scaled; rotation commutes.
__global__ __launch_bounds__(256) void rope_bf_k(short* __restrict__ q,
                                                 short* __restrict__ kk,
                                                 const float* __restrict__ pos) {
  const int idx = blockIdx.x * 256 + threadIdx.x;   // 32768
  const int row = idx >> 2, hh = idx & 3;
  const float2 pp = *(const float2*)&pos[(size_t)row * 2];
  short* qp = q + (size_t)row * DIM + hh * HD;
  short* kp = kk + (size_t)row * DIM + hh * HD;
  bf16x8 qv[4], kv[4];
#pragma unroll
  for (int u = 0; u < 4; u++) {
    qv[u] = *(const bf16x8*)(qp + 8 * u);
    kv[u] = *(const bf16x8*)(kp + 8 * u);
  }
#pragma unroll
  for (int lp = 0; lp < 16; lp++) {
    const int p = hh * 16 + lp;
    const float coord = (p < 32) ? pp.x : pp.y;
    const int f = p & 31;
    float sn, cs;
    __sincosf(3.14159265358979323846f * (float)(f + 1) * coord, &sn, &cs);
    const int u = lp >> 2, e = (lp & 3) * 2;
    const float a0 = __uint_as_float(((unsigned)(unsigned short)qv[u][e]) << 16);
    const float a1 = __uint_as_float(((unsigned)(unsigned short)qv[u][e + 1]) << 16);
    qv[u][e]     = (short)f2bf(cs * a0 - sn * a1);
    qv[u][e + 1] = (short)f2bf(cs * a1 + sn * a0);
    const float b0 = __uint_as_float(((unsigned)(unsigned short)kv[u][e]) << 16);
    const float b1 = __uint_as_float(((unsigned)(unsigned short)kv[u][e + 1]) << 16);
    kv[u][e]     = (short)f2bf(cs * b0 - sn * b1);
    kv[u][e + 1] = (short)f2bf(cs * b1 + sn * b0);
  }
#pragma unroll
  for (int u = 0; u < 4; u++) {
    *(bf16x8*)(qp + 8 * u) = qv[u];
    *(bf16x8*)(kp + 8 * u) = kv[u];
  }
}

// ---------------------------------------------------------------------------
// MFMA flash attention, KV-split partials, NO online max (exp2-domain scores
// are bounded; softmax is shift-invariant so partial sums are associative).
// grid (N/32, B*H, NCH) x 128 threads (2 waves). Writes unnormalized
// acc (fp32) and l per chunk; attn_comb_k reduces over chunks.
__global__ __launch_bounds__(128) void attn4_k(const short* __restrict__ q,
                                               const short* __restrict__ k,
                                               const short* __restrict__ vt,
                                               const float* __restrict__ pos,
                                               float* __restrict__ accP,
                                               float* __restrict__ lP) {
  const int bh = blockIdx.y, b = bh >> 2, h = bh & 3;
  const int q0 = blockIdx.x * 32;
  const int ch = blockIdx.z;
  const int kbeg = ch * CHLEN, kend = kbeg + CHLEN;
  __shared__ short ks_s[64 * 40];
  __shared__ short vt_s[32 * 72];
  __shared__ short ps_s[2 * 16 * 72];
  __shared__ float pkx[64], pky[64], pnt[64];
  const int t = threadIdx.x, w = t >> 6, lane = t & 63, g = lane >> 4, i16 = lane & 15;
  const short* kp = k + (size_t)b * NN * DIM + h * HD;
  const short* vp = vt + (size_t)bh * HD * NN;

  const bf16x8 qf = *(const bf16x8*)(q + (size_t)(b * NN + q0 + 16 * w + i16) * DIM + h * HD + 8 * g);
  const float2 qp2 = *(const float2*)&pos[((size_t)b * NN + q0 + 16 * w + i16) * 2];
  const float qx = qp2.x, qy = qp2.y;
  const float ci = 0.5f * (qx * qx + qy * qy) - 0.5f * R2;

  // prefetch first tile of this chunk
  bf16x8 kreg0 = *(const bf16x8*)(kp + (size_t)(kbeg + (t >> 2)) * DIM + (t & 3) * 8);
  bf16x8 kreg1 = *(const bf16x8*)(kp + (size_t)(kbeg + 32 + (t >> 2)) * DIM + (t & 3) * 8);
  bf16x8 vreg0 = *(const bf16x8*)(vp + (size_t)(t >> 3) * NN + kbeg + (t & 7) * 8);
  bf16x8 vreg1 = *(const bf16x8*)(vp + (size_t)((t >> 3) + 16) * NN + kbeg + (t & 7) * 8);
  float2 kpos = make_float2(0.f, 0.f);
  if (t < 64) kpos = *(const float2*)&pos[((size_t)b * NN + kbeg + t) * 2];

  f32x4 acc0 = {0.f, 0.f, 0.f, 0.f}, acc1 = {0.f, 0.f, 0.f, 0.f};
  const f32x4 zf = {0.f, 0.f, 0.f, 0.f};
  float l_run = 0.f;

  for (int k0 = kbeg; k0 < kend; k0 += 64) {
    __syncthreads();
    *(bf16x8*)&ks_s[(t >> 2) * 40 + (t & 3) * 8] = kreg0;
    *(bf16x8*)&ks_s[((t >> 2) + 32) * 40 + (t & 3) * 8] = kreg1;
    *(bf16x8*)&vt_s[(t >> 3) * 72 + (t & 7) * 8] = vreg0;
    *(bf16x8*)&vt_s[((t >> 3) + 16) * 72 + (t & 7) * 8] = vreg1;
    if (t < 64) {
      pkx[t] = kpos.x; pky[t] = kpos.y;
      pnt[t] = -0.5f * (kpos.x * kpos.x + kpos.y * kpos.y);
    }
    __syncthreads();
    const int kn = k0 + 64;
    if (kn < kend) {
      kreg0 = *(const bf16x8*)(kp + (size_t)(kn + (t >> 2)) * DIM + (t & 3) * 8);
      kreg1 = *(const bf16x8*)(kp + (size_t)(kn + 32 + (t >> 2)) * DIM + (t & 3) * 8);
      vreg0 = *(const bf16x8*)(vp + (size_t)(t >> 3) * NN + kn + (t & 7) * 8);
      vreg1 = *(const bf16x8*)(vp + (size_t)((t >> 3) + 16) * NN + kn + (t & 7) * 8);
      if (t < 64) kpos = *(const float2*)&pos[((size_t)b * NN + kn + t) * 2];
    }

    // --- QK^T (swapped): sx[jt][r] = S2[key 16jt+4g+r][query i16] (exp2 dom)
    f32x4 sx[4];
#pragma unroll
    for (int jt = 0; jt < 4; jt++) {
      bf16x8 kf = *(const bf16x8*)&ks_s[(16 * jt + i16) * 40 + 8 * g];
      sx[jt] = __builtin_amdgcn_mfma_f32_16x16x32_bf16(kf, qf, zf, 0, 0, 0);
    }

    // --- mask + exp2 (no max tracking: P = exp2(S), masked -> 0) ---
    float pr[16];
    float tsum = 0.f;
#pragma unroll
    for (int jt = 0; jt < 4; jt++) {
      float4 kx4 = *(const float4*)&pkx[16 * jt + 4 * g];
      float4 ky4 = *(const float4*)&pky[16 * jt + 4 * g];
      float4 nt4 = *(const float4*)&pnt[16 * jt + 4 * g];
      const float kxa[4] = {kx4.x, kx4.y, kx4.z, kx4.w};
      const float kya[4] = {ky4.x, ky4.y, ky4.z, ky4.w};
      const float nta[4] = {nt4.x, nt4.y, nt4.z, nt4.w};
#pragma unroll
      for (int r = 0; r < 4; r++) {
        const float dot = fmaf(qx, kxa[r], fmaf(qy, kya[r], nta[r]));
        float p = exp2_fast(sx[jt][r]);
        p = (dot >= ci) ? p : 0.f;
        pr[jt * 4 + r] = p;
        tsum += p;
      }
    }
    l_run += tsum;   // cross-lane reduce deferred to epilogue (plain sum)

    // P rows -> per-wave LDS (packed bf16 via v_cvt_pk_bf16_f32)
#pragma unroll
    for (int jt = 0; jt < 4; jt++) {
      uint2 w2;
      w2.x = cvt_pk_bf16(pr[jt * 4 + 0], pr[jt * 4 + 1]);
      w2.y = cvt_pk_bf16(pr[jt * 4 + 2], pr[jt * 4 + 3]);
      *(uint2*)&ps_s[w * 1152 + i16 * 72 + 16 * jt + 4 * g] = w2;
    }

    // --- PV (no rescale needed) ---
#pragma unroll
    for (int ks2 = 0; ks2 < 2; ks2++) {
      bf16x8 pf = *(const bf16x8*)&ps_s[w * 1152 + i16 * 72 + 8 * g + 32 * ks2];
      bf16x8 vf0 = *(const bf16x8*)&vt_s[i16 * 72 + 8 * g + 32 * ks2];
      bf16x8 vf1 = *(const bf16x8*)&vt_s[(16 + i16) * 72 + 8 * g + 32 * ks2];
      acc0 = __builtin_amdgcn_mfma_f32_16x16x32_bf16(pf, vf0, acc0, 0, 0, 0);
      acc1 = __builtin_amdgcn_mfma_f32_16x16x32_bf16(pf, vf1, acc1, 0, 0, 0);
    }
  }

  // epilogue: write unnormalized partials
  l_run += __shfl_xor(l_run, 16, 64);
  l_run += __shfl_xor(l_run, 32, 64);
  if (lane < 16)
    lP[(size_t)(ch * 8 + bh) * NN + q0 + 16 * w + lane] = l_run;
  float* ap = accP + ((size_t)(ch * 8 + bh) * NN + q0 + 16 * w) * HD;
#pragma unroll
  for (int r = 0; r < 4; r++) {
    ap[(4 * g + r) * HD + i16] = acc0[r];
    ap[(4 * g + r) * HD + 16 + i16] = acc1[r];
  }
}

// ---------------------------------------------------------------------------
// Combine KV-split partials: O = sum_c acc / sum_c l, write bf16 interleaved.
// grid 1024 x 256; 32 threads cover one (b,n) row (4 heads x 8 d-quads).
__global__ __launch_bounds__(256) void attn_comb_k(const float* __restrict__ accP,
                                                   const float* __restrict__ lP,
                                                   short* __restrict__ ob) {
  const int idx = blockIdx.x * 256 + threadIdx.x;   // 262144
  const int b = idx >> 17;
  const int n = (idx >> 5) & (NN - 1);
  const int hd = idx & 31;
  const int h = hd >> 3, d4 = (hd & 7) * 4;
  const int bh = b * NH + h;
  float ax = 0.f, ay = 0.f, az = 0.f, aw = 0.f, l = 0.f;
#pragma unroll
  for (int c = 0; c < NCH; c++) {
    const float4 v = *(const float4*)&accP[((size_t)(c * 8 + bh) * NN + n) * HD + d4];
    ax += v.x; ay += v.y; az += v.z; aw += v.w;
    l += lP[(size_t)(c * 8 + bh) * NN + n];
  }
  const float inv = 1.0f / l;
  bf16x4 o;
  o[0] = (short)f2bf(ax * inv);
  o[1] = (short)f2bf(ay * inv);
  o[2] = (short)f2bf(az * inv);
  o[3] = (short)f2bf(aw * inv);
  *(bf16x4*)&ob[((size_t)b * NN + n) * DIM + h * HD + d4] = o;
}

// ---------------------------------------------------------------------------
extern "C" void kernel_launch(void* const* d_in, const int* in_sizes, int n_in,
                              void* d_out, int out_size, void* d_ws, size_t ws_size,
                              hipStream_t stream) {
  const float* x = (const float*)d_in[0];
  const float* pos = (const float*)d_in[1];
  const float* Wq_w = (const float*)d_in[2];
  const float* Wq_b = (const float*)d_in[3];
  const float* Wk_w = (const float*)d_in[4];
  const float* Wk_b = (const float*)d_in[5];
  const float* Wv_w = (const float*)d_in[6];
  const float* Wv_b = (const float*)d_in[7];
  const float* Wo_w = (const float*)d_in[8];
  const float* Wo_b = (const float*)d_in[9];
  const float* n1_g = (const float*)d_in[10];
  const float* n1_b = (const float*)d_in[11];
  const float* n2_g = (const float*)d_in[12];
  const float* n2_b = (const float*)d_in[13];
  const float* l1_w = (const float*)d_in[14];
  const float* l1_b = (const float*)d_in[15];
  const float* l2_w = (const float*)d_in[16];
  const float* l2_b = (const float*)d_in[17];

  float* out = (float*)d_out;
  short* wsS = (short*)d_ws;
  const size_t MN = (size_t)MROWS * DIM;   // 1048576
  // shorts region: q,k,vt,ob + wT  (~8.9 MB)
  short* qb_bf = wsS;                      // q [M][128], k at +MN, vt at +2MN
  short* ob_bf = wsS + 3 * MN;             // [M][128]
  short* wT    = wsS + 4 * MN;             // 262144 shorts
  // floats region (~17.3 MB)
  float* fbase = (float*)(wsS + 4 * MN + 262144);
  float* qkvb  = fbase;                    // 768
  float* sums  = fbase + 768;              // 1280 (5 slots x 256)
  float* lP    = fbase + 2048;             // NCH*8*NN = 131072
  float* accP  = fbase + 2048 + 131072;    // NCH*8*NN*HD = 4194304
  short* hb_bf = (short*)accP;             // FFN hidden aliases accP (disjoint phases)

  wprep_k<<<256, 256, 0, stream>>>(Wq_w, Wk_w, Wv_w, Wo_w, l1_w, l2_w,
                                   Wq_b, Wk_b, Wv_b, wT, qkvb);
  hipMemsetAsync(sums, 0, 1280 * sizeof(float), stream);
  copy_stats_k<<<256, 256, 0, stream>>>(x, out, sums);   // slot 0 = n1, l0

  for (int l = 0; l < LYR; l++) {
    const short* lw = wT + (size_t)l * 131072;
    float* s_n1 = sums + (2 * l) * 256;
    float* s_n2 = sums + (2 * l + 1) * 256;
    float* s_nx = sums + (2 * l + 2) * 256;   // next layer's n1 (or dummy)

    // --- attention block (BN fused into QKV GEMM A-load) ---
    gemm_bf_k<3, false, true><<<dim3(128, 6), 256, 0, stream>>>(
        nullptr, out, s_n1, n1_g + l * DIM, n1_b + l * DIM,
        lw, qkvb + l * 384, nullptr, nullptr, qb_bf, nullptr, 128);
    if (l == 0) rope_bf_k<<<128, 256, 0, stream>>>(qb_bf, qb_bf + MN, pos);
    attn4_k<<<dim3(NN / 32, BB * NH, NCH), 128, 0, stream>>>(
        qb_bf, qb_bf + MN, qb_bf + 2 * MN, pos, accP, lP);
    attn_comb_k<<<1024, 256, 0, stream>>>(accP, lP, ob_bf);
    gemm_bf_k<0, false, false><<<dim3(128, 2), 256, 0, stream>>>(
        ob_bf, nullptr, nullptr, nullptr, nullptr,
        lw + 49152, Wo_b + l * DIM, out, out, nullptr, s_n2, 128);

    // --- FFN block (BN fused into FFN1 GEMM A-load) ---
    gemm_bf_k<1, true, true><<<dim3(128, 4), 256, 0, stream>>>(
        nullptr, out, s_n2, n2_g + l * DIM, n2_b + l * DIM,
        lw + 65536, l1_b + l * 2 * DIM, nullptr, nullptr, hb_bf, nullptr, 128);
    gemm_bf_k<0, false, false><<<dim3(128, 2), 256, 0, stream>>>(
        hb_bf, nullptr, nullptr, nullptr, nullptr,
        lw + 98304, l2_b + l * DIM, out, out, nullptr, s_nx, 256);
  }
}